// Round 1
// baseline (204.638 us; speedup 1.0000x reference)
//
#include <hip/hip_runtime.h>
#include <hip/hip_bf16.h>
#include <math.h>

// Sizes (compile-time constants from the reference)
static constexpr int Dd   = 128;   // d_model
static constexpr int NH   = 8;     // heads
static constexpr int HD   = 16;    // head dim
static constexpr int NE   = 256;   // experts
static constexpr int RR   = 32;    // kv lora rank
static constexpr int BB   = 4;
static constexpr int TT   = 512;
static constexpr int NTOK = BB * TT;   // 2048
static constexpr int TPB  = 4;         // tokens per block
#define EPSF 1e-6f

__device__ __forceinline__ float elu1(float v) { return v > 0.f ? v + 1.f : expf(v); }
__device__ __forceinline__ float sigm(float v) { return 1.f / (1.f + expf(-v)); }

// 4 independent 128-wide sums (one per token). 128 threads = 2 waves.
__device__ __forceinline__ void block_sum4(float v[TPB], float out[TPB],
                                           float (*tmp)[TPB], int tid) {
#pragma unroll
  for (int o = 32; o > 0; o >>= 1) {
#pragma unroll
    for (int t = 0; t < TPB; t++) v[t] += __shfl_xor(v[t], o, 64);
  }
  int wave = tid >> 6, lane = tid & 63;
  if (lane == 0) {
#pragma unroll
    for (int t = 0; t < TPB; t++) tmp[wave][t] = v[t];
  }
  __syncthreads();
#pragma unroll
  for (int t = 0; t < TPB; t++) out[t] = tmp[0][t] + tmp[1][t];
  __syncthreads();
}

// 4 independent argmax (val desc, idx asc tie-break)
__device__ __forceinline__ void block_argmax4(float v[TPB], int idx[TPB],
                                              float ov[TPB], int oi[TPB],
                                              float (*tv)[TPB], int (*ti)[TPB], int tid) {
#pragma unroll
  for (int o = 32; o > 0; o >>= 1) {
#pragma unroll
    for (int t = 0; t < TPB; t++) {
      float wv = __shfl_xor(v[t], o, 64);
      int   wi = __shfl_xor(idx[t], o, 64);
      if (wv > v[t] || (wv == v[t] && wi < idx[t])) { v[t] = wv; idx[t] = wi; }
    }
  }
  int wave = tid >> 6, lane = tid & 63;
  if (lane == 0) {
#pragma unroll
    for (int t = 0; t < TPB; t++) { tv[wave][t] = v[t]; ti[wave][t] = idx[t]; }
  }
  __syncthreads();
#pragma unroll
  for (int t = 0; t < TPB; t++) {
    float a = tv[0][t], b = tv[1][t];
    int ia = ti[0][t], ib = ti[1][t];
    if (b > a || (b == a && ib < ia)) { ov[t] = b; oi[t] = ib; }
    else                             { ov[t] = a; oi[t] = ia; }
  }
  __syncthreads();
}

// Kernel A: rmsnorm1 -> q proj (+elu+1) -> kd -> ku (+elu+1 on k half)
__global__ __launch_bounds__(128) void k_qkv(
    const float* __restrict__ x, const float* __restrict__ g1,
    const float* __restrict__ qW, const float* __restrict__ qb,
    const float* __restrict__ kdW, const float* __restrict__ kdb,
    const float* __restrict__ kuW, const float* __restrict__ kub,
    float* __restrict__ qout, float* __restrict__ kvout) {
  const int j  = threadIdx.x;
  const int n0 = blockIdx.x * TPB;
  __shared__ float h1[TPB][Dd];
  __shared__ float kd[TPB][RR];
  __shared__ float rtmp[2][TPB];

  float xv[TPB], sq[TPB], ss[TPB];
#pragma unroll
  for (int t = 0; t < TPB; t++) { xv[t] = x[(n0 + t) * Dd + j]; sq[t] = xv[t] * xv[t]; }
  block_sum4(sq, ss, rtmp, j);
  float g1j = g1[j];
#pragma unroll
  for (int t = 0; t < TPB; t++) h1[t][j] = g1j * xv[t] * rsqrtf(ss[t] * (1.f / 128.f) + EPSF);
  __syncthreads();

  { // q = h1 @ qW + qb, elu+1
    float acc[TPB];
#pragma unroll
    for (int t = 0; t < TPB; t++) acc[t] = qb[j];
    for (int i = 0; i < Dd; i++) {
      float w = qW[i * Dd + j];
#pragma unroll
      for (int t = 0; t < TPB; t++) acc[t] += h1[t][i] * w;
    }
#pragma unroll
    for (int t = 0; t < TPB; t++) qout[(n0 + t) * Dd + j] = elu1(acc[t]);
  }

  if (j < RR) { // kd = h1 @ kdW + kdb
    float acc[TPB];
#pragma unroll
    for (int t = 0; t < TPB; t++) acc[t] = kdb[j];
    for (int i = 0; i < Dd; i++) {
      float w = kdW[i * RR + j];
#pragma unroll
      for (int t = 0; t < TPB; t++) acc[t] += h1[t][i] * w;
    }
#pragma unroll
    for (int t = 0; t < TPB; t++) kd[t][j] = acc[t];
  }
  __syncthreads();

  { // kv = kd @ kuW + kub; k half gets elu+1
    int c0 = j, c1 = j + 128;
    float a0[TPB], a1[TPB];
#pragma unroll
    for (int t = 0; t < TPB; t++) { a0[t] = kub[c0]; a1[t] = kub[c1]; }
    for (int r = 0; r < RR; r++) {
      float w0 = kuW[r * 2 * Dd + c0], w1 = kuW[r * 2 * Dd + c1];
#pragma unroll
      for (int t = 0; t < TPB; t++) { float kv = kd[t][r]; a0[t] += kv * w0; a1[t] += kv * w1; }
    }
    bool isk = (j & 31) < 16; // same for c0 and c1 (c1 = c0+128, 128%32==0)
#pragma unroll
    for (int t = 0; t < TPB; t++) {
      kvout[(n0 + t) * 256 + c0] = isk ? elu1(a0[t]) : a0[t];
      kvout[(n0 + t) * 256 + c1] = isk ? elu1(a1[t]) : a1[t];
    }
  }
}

// Kernel B: context[b,h,d,e] = sum_t k*v ; k_sum[b,h,d]
__global__ __launch_bounds__(256) void k_ctx(const float* __restrict__ kv,
                                             float* __restrict__ ctx,
                                             float* __restrict__ ksum) {
  const int bh = blockIdx.x;       // 0..31
  const int b = bh >> 3, h = bh & 7;
  const int tid = threadIdx.x;
  const int d = tid >> 4, e = tid & 15;
  __shared__ float sh[64 * 32];
  float acc = 0.f, ks = 0.f;
  for (int c = 0; c < 8; c++) {
#pragma unroll
    for (int r = 0; r < 8; r++) {
      int lin = r * 256 + tid;
      int tok = lin >> 5, off = lin & 31;
      sh[lin] = kv[((b * TT + c * 64 + tok) * 256) + h * 32 + off];
    }
    __syncthreads();
    for (int t = 0; t < 64; t++) {
      float kk = sh[t * 32 + d];
      acc += kk * sh[t * 32 + 16 + e];
      ks += kk;
    }
    __syncthreads();
  }
  ctx[bh * 256 + d * 16 + e] = acc;
  if (e == 0) ksum[bh * 16 + d] = ks;
}

// Kernel C: everything else, per 4 tokens
__global__ __launch_bounds__(128) void k_fuse(
    const float* __restrict__ x, const float* __restrict__ qbuf,
    const float* __restrict__ ctx, const float* __restrict__ ksum,
    const float* __restrict__ oW, const float* __restrict__ ob,
    const float* __restrict__ rot, const float* __restrict__ tqs,
    const float* __restrict__ s1W, const float* __restrict__ s1b,
    const float* __restrict__ s2W, const float* __restrict__ s2b,
    const float* __restrict__ g2, const float* __restrict__ gateW,
    const float* __restrict__ gateb, const float* __restrict__ expW,
    const float* __restrict__ m1W, const float* __restrict__ m1b,
    const float* __restrict__ m2W, const float* __restrict__ m2b,
    float* __restrict__ out) {
  const int j  = threadIdx.x;
  const int n0 = blockIdx.x * TPB;
  const int b  = n0 >> 9;
  __shared__ float sA[TPB][Dd];
  __shared__ float sB[TPB][Dd];
  __shared__ float sLG[TPB][NE];
  __shared__ float rtmp[2][TPB];
  __shared__ float rtv[2][TPB];
  __shared__ int   rti[2][TPB];
  __shared__ int   s_i1[TPB], s_i2[TPB];
  __shared__ float s_w1[TPB], s_w2[TPB];

  // 1) load q
#pragma unroll
  for (int t = 0; t < TPB; t++) sA[t][j] = qbuf[(n0 + t) * Dd + j];
  __syncthreads();

  // 2) attention apply: out = (q @ ctx) / (q . ksum + eps)  -> sB
  {
    const int h = j >> 4, e = j & 15;
    const float* cpt = ctx + (b * NH + h) * HD * HD;
    const float* kpt = ksum + (b * NH + h) * HD;
    float num[TPB] = {0, 0, 0, 0}, den[TPB] = {0, 0, 0, 0};
#pragma unroll
    for (int d = 0; d < HD; d++) {
      float cx = cpt[d * HD + e];
      float ks = kpt[d];
#pragma unroll
      for (int t = 0; t < TPB; t++) {
        float qd = sA[t][h * HD + d];
        num[t] += qd * cx;
        den[t] += qd * ks;
      }
    }
#pragma unroll
    for (int t = 0; t < TPB; t++) sB[t][j] = num[t] / (den[t] + EPSF);
    __syncthreads();
  }

  // 3) attn = sB @ oW + ob -> sA
  {
    float acc[TPB];
#pragma unroll
    for (int t = 0; t < TPB; t++) acc[t] = ob[j];
    for (int i = 0; i < Dd; i++) {
      float w = oW[i * Dd + j];
#pragma unroll
      for (int t = 0; t < TPB; t++) acc[t] += sB[t][i] * w;
    }
#pragma unroll
    for (int t = 0; t < TPB; t++) sA[t][j] = acc[t];
    __syncthreads();
  }

  // 4) y = sA @ rot; turbo-quant (clamp(phase,±1)*mag*scale) -> sA
  {
    float acc[TPB];
#pragma unroll
    for (int t = 0; t < TPB; t++) acc[t] = 0.f;
    for (int i = 0; i < Dd; i++) {
      float w = rot[i * Dd + j];
#pragma unroll
      for (int t = 0; t < TPB; t++) acc[t] += sA[t][i] * w;
    }
    float sq[TPB], ss[TPB];
#pragma unroll
    for (int t = 0; t < TPB; t++) sq[t] = acc[t] * acc[t];
    block_sum4(sq, ss, rtmp, j);   // barrier: all sA reads done
    float scj = tqs[j];
#pragma unroll
    for (int t = 0; t < TPB; t++) {
      float mag = sqrtf(ss[t] * (1.f / 128.f) + EPSF);
      float ph = acc[t] / mag;
      float p127 = fminf(fmaxf(ph * 127.f, -127.f), 127.f);
      sA[t][j] = (p127 * (1.f / 127.f)) * mag * scj;
    }
    __syncthreads();
  }

  // 5) swiglu1 + residual -> xn in sB ; 6) rmsnorm2 -> sA
  {
    float g[TPB], u[TPB];
#pragma unroll
    for (int t = 0; t < TPB; t++) { g[t] = s1b[j]; u[t] = s2b[j]; }
    for (int i = 0; i < Dd; i++) {
      float w1 = s1W[i * Dd + j], w2 = s2W[i * Dd + j];
#pragma unroll
      for (int t = 0; t < TPB; t++) { float a = sA[t][i]; g[t] += a * w1; u[t] += a * w2; }
    }
    float sq[TPB], ss[TPB];
#pragma unroll
    for (int t = 0; t < TPB; t++) {
      float gv = g[t];
      float xn = x[(n0 + t) * Dd + j] + gv * sigm(gv) * u[t];
      sB[t][j] = xn;
      sq[t] = xn * xn;
    }
    block_sum4(sq, ss, rtmp, j);   // barrier: all sA (aq) reads done
    float g2j = g2[j];
#pragma unroll
    for (int t = 0; t < TPB; t++) sA[t][j] = g2j * sB[t][j] * rsqrtf(ss[t] * (1.f / 128.f) + EPSF);
    __syncthreads();
  }

  // 7) gate logits -> sLG
  {
    float a0[TPB], a1[TPB];
#pragma unroll
    for (int t = 0; t < TPB; t++) { a0[t] = gateb[j]; a1[t] = gateb[j + 128]; }
    for (int i = 0; i < Dd; i++) {
      float w0 = gateW[i * NE + j], w1 = gateW[i * NE + j + 128];
#pragma unroll
      for (int t = 0; t < TPB; t++) { float h2 = sA[t][i]; a0[t] += h2 * w0; a1[t] += h2 * w1; }
    }
#pragma unroll
    for (int t = 0; t < TPB; t++) { sLG[t][j] = a0[t]; sLG[t][j + 128] = a1[t]; }
    __syncthreads();
  }

  // 8) softmax + top2 + normalized weights
  {
    float v[TPB]; int idx[TPB];
#pragma unroll
    for (int t = 0; t < TPB; t++) {
      float l0 = sLG[t][j], l1 = sLG[t][j + 128];
      if (l0 >= l1) { v[t] = l0; idx[t] = j; } else { v[t] = l1; idx[t] = j + 128; }
    }
    float m1v[TPB]; int i1v[TPB];
    block_argmax4(v, idx, m1v, i1v, rtv, rti, j);
    float v2[TPB]; int idx2[TPB];
#pragma unroll
    for (int t = 0; t < TPB; t++) {
      float l0 = (j == i1v[t]) ? -INFINITY : sLG[t][j];
      float l1 = (j + 128 == i1v[t]) ? -INFINITY : sLG[t][j + 128];
      if (l0 >= l1) { v2[t] = l0; idx2[t] = j; } else { v2[t] = l1; idx2[t] = j + 128; }
    }
    float m2v[TPB]; int i2v[TPB];
    block_argmax4(v2, idx2, m2v, i2v, rtv, rti, j);
    float se[TPB], Z[TPB];
#pragma unroll
    for (int t = 0; t < TPB; t++)
      se[t] = expf(sLG[t][j] - m1v[t]) + expf(sLG[t][j + 128] - m1v[t]);
    block_sum4(se, Z, rtmp, j);
    if (j == 0) {
#pragma unroll
      for (int t = 0; t < TPB; t++) {
        float p1 = 1.f / Z[t];
        float p2 = expf(m2v[t] - m1v[t]) / Z[t];
        float s = p1 + p2 + EPSF;
        s_i1[t] = i1v[t]; s_i2[t] = i2v[t];
        s_w1[t] = p1 / s; s_w2[t] = p2 / s;
      }
    }
    __syncthreads();
  }

  // 9) top-2 expert GEMVs; wavg0 -> sLG[t][0..127]
  float y1[TPB], y2[TPB];
  {
#pragma unroll
    for (int t = 0; t < TPB; t++) {
      const float* W1 = expW + (size_t)s_i1[t] * Dd * Dd;
      const float* W2 = expW + (size_t)s_i2[t] * Dd * Dd;
      float a1 = 0.f, a2 = 0.f;
      for (int i = 0; i < Dd; i++) {
        float h2 = sA[t][i];
        a1 += h2 * W1[i * Dd + j];
        a2 += h2 * W2[i * Dd + j];
      }
      y1[t] = a1; y2[t] = a2;
      sLG[t][j] = s_w1[t] * a1 + s_w2[t] * a2;
    }
    __syncthreads();
  }

  // 10) m-swiglu, wvar, consensus, final residual
  {
    float g[TPB], u[TPB];
#pragma unroll
    for (int t = 0; t < TPB; t++) { g[t] = m1b[j]; u[t] = m2b[j]; }
    for (int i = 0; i < Dd; i++) {
      float w1 = m1W[i * Dd + j], w2 = m2W[i * Dd + j];
#pragma unroll
      for (int t = 0; t < TPB; t++) { float a = sLG[t][i]; g[t] += a * w1; u[t] += a * w2; }
    }
    float wv[TPB], vv[TPB], sv[TPB];
#pragma unroll
    for (int t = 0; t < TPB; t++) {
      float gv = g[t];
      wv[t] = gv * sigm(gv) * u[t];
      float d1 = y1[t] - wv[t], d2 = y2[t] - wv[t];
      vv[t] = s_w1[t] * d1 * d1 + s_w2[t] * d2 * d2;
    }
    block_sum4(vv, sv, rtmp, j);
#pragma unroll
    for (int t = 0; t < TPB; t++) out[(n0 + t) * Dd + j] = sB[t][j] + wv[t];
    if (j == 0) {
#pragma unroll
      for (int t = 0; t < TPB; t++) out[NTOK * Dd + n0 + t] = expf(-sv[t] * (1.f / 128.f));
    }
  }
}

extern "C" void kernel_launch(void* const* d_in, const int* in_sizes, int n_in,
                              void* d_out, int out_size, void* d_ws, size_t ws_size,
                              hipStream_t stream) {
  const float* x   = (const float*)d_in[0];
  const float* g1  = (const float*)d_in[1];
  const float* qW  = (const float*)d_in[2];
  const float* qb  = (const float*)d_in[3];
  const float* kdW = (const float*)d_in[4];
  const float* kdb = (const float*)d_in[5];
  const float* kuW = (const float*)d_in[6];
  const float* kub = (const float*)d_in[7];
  const float* oW  = (const float*)d_in[8];
  const float* ob  = (const float*)d_in[9];
  const float* rot = (const float*)d_in[10];
  const float* tqs = (const float*)d_in[11];
  const float* s1W = (const float*)d_in[12];
  const float* s1b = (const float*)d_in[13];
  const float* s2W = (const float*)d_in[14];
  const float* s2b = (const float*)d_in[15];
  const float* g2  = (const float*)d_in[16];
  const float* gW  = (const float*)d_in[17];
  const float* gb  = (const float*)d_in[18];
  const float* eW  = (const float*)d_in[19];
  const float* m1W = (const float*)d_in[20];
  const float* m1b = (const float*)d_in[21];
  const float* m2W = (const float*)d_in[22];
  const float* m2b = (const float*)d_in[23];
  float* out = (float*)d_out;
  float* ws  = (float*)d_ws;

  float* qbuf  = ws;                 // 2048*128 = 262144
  float* kvbuf = ws + 262144;        // 2048*256 = 524288
  float* ctx   = ws + 786432;        // 4*8*256  = 8192
  float* ksum  = ws + 794624;        // 4*8*16   = 512

  k_qkv<<<NTOK / TPB, 128, 0, stream>>>(x, g1, qW, qb, kdW, kdb, kuW, kub, qbuf, kvbuf);
  k_ctx<<<32, 256, 0, stream>>>(kvbuf, ctx, ksum);
  k_fuse<<<NTOK / TPB, 128, 0, stream>>>(x, qbuf, ctx, ksum, oW, ob, rot, tqs,
                                         s1W, s1b, s2W, s2b, g2, gW, gb, eW,
                                         m1W, m1b, m2W, m2b, out);
}

// Round 2
// 195.511 us; speedup vs baseline: 1.0467x; 1.0467x over previous
//
#include <hip/hip_runtime.h>
#include <hip/hip_bf16.h>
#include <math.h>

static constexpr int Dd   = 128;
static constexpr int NH   = 8;
static constexpr int HD   = 16;
static constexpr int NE   = 256;
static constexpr int RR   = 32;
static constexpr int BB   = 4;
static constexpr int TT   = 512;
static constexpr int NTOK = BB * TT;   // 2048
static constexpr int TPB  = 4;
#define EPSF 1e-6f

__device__ __forceinline__ float elu1(float v) { return v > 0.f ? v + 1.f : expf(v); }
__device__ __forceinline__ float sigm(float v) { return 1.f / (1.f + expf(-v)); }

// ---------------- k_pre: rmsnorm1 + q proj(+elu) + kd + ku(+elu on k half) ---
// 256 threads: j=tid&127 (output col), g=tid>>7 (K-half for 128-K GEMVs)
__global__ __launch_bounds__(256) void k_pre(
    const float* __restrict__ x, const float* __restrict__ g1,
    const float* __restrict__ qW, const float* __restrict__ qb,
    const float* __restrict__ kdW, const float* __restrict__ kdb,
    const float* __restrict__ kuW, const float* __restrict__ kub,
    float* __restrict__ qbuf, float* __restrict__ kvbuf,
    float* __restrict__ ctx, float* __restrict__ ksum, int* __restrict__ cnt) {
  const int tid = threadIdx.x;
  const int j = tid & 127, g = tid >> 7;
  const int lane = tid & 63, wid = tid >> 6;
  const int n0 = blockIdx.x * TPB;

  __shared__ float4 h1T[128];
  __shared__ float4 part0[128];
  __shared__ float4 kpart[4][32];
  __shared__ float4 kdT[32];
  __shared__ float4 rtmp[2];

  if (blockIdx.x == 0) {  // zero accumulators for later kernels
    for (int i = tid; i < 32 * 256; i += 256) ctx[i] = 0.f;
    for (int i = tid; i < 32 * 16; i += 256) ksum[i] = 0.f;
    cnt[tid] = 0;
  }

  // rmsnorm1 (g0 only computes; all threads hit barriers)
  float xv[4];
  if (g == 0) {
    float v[4];
#pragma unroll
    for (int t = 0; t < 4; t++) { xv[t] = x[(n0 + t) * Dd + j]; v[t] = xv[t] * xv[t]; }
#pragma unroll
    for (int o = 32; o > 0; o >>= 1) {
#pragma unroll
      for (int t = 0; t < 4; t++) v[t] += __shfl_xor(v[t], o, 64);
    }
    if (lane == 0) rtmp[wid] = make_float4(v[0], v[1], v[2], v[3]);
  }
  __syncthreads();
  if (g == 0) {
    float g1j = g1[j];
#pragma unroll
    for (int t = 0; t < 4; t++) {
      float ss = ((const float*)&rtmp[0])[t] + ((const float*)&rtmp[1])[t];
      ((float*)&h1T[j])[t] = g1j * xv[t] * rsqrtf(ss * (1.f / 128.f) + EPSF);
    }
  }
  __syncthreads();

  // q GEMV (K-split 2) -> elu1 -> qbuf
  {
    float a0 = 0, a1 = 0, a2 = 0, a3 = 0;
    const float* Wp = qW + (g * 64) * Dd + j;
#pragma unroll 8
    for (int i = 0; i < 64; i++) {
      float4 h4 = h1T[g * 64 + i];
      float w = Wp[i * Dd];
      a0 += h4.x * w; a1 += h4.y * w; a2 += h4.z * w; a3 += h4.w * w;
    }
    if (g == 1) part0[j] = make_float4(a0, a1, a2, a3);
    __syncthreads();
    if (g == 0) {
      float4 p = part0[j];
      float bb = qb[j];
      float q0 = a0 + p.x + bb, q1 = a1 + p.y + bb, q2 = a2 + p.z + bb, q3 = a3 + p.w + bb;
      qbuf[(n0 + 0) * Dd + j] = elu1(q0);
      qbuf[(n0 + 1) * Dd + j] = elu1(q1);
      qbuf[(n0 + 2) * Dd + j] = elu1(q2);
      qbuf[(n0 + 3) * Dd + j] = elu1(q3);
    }
  }

  // kd GEMV: 32 cols x 4 K-splits (threads tid<128)
  if (tid < 128) {
    int col = tid & 31, ksp = tid >> 5;
    float a0 = 0, a1 = 0, a2 = 0, a3 = 0;
    const float* Wp = kdW + (ksp * 32) * RR + col;
#pragma unroll 8
    for (int i = 0; i < 32; i++) {
      float4 h4 = h1T[ksp * 32 + i];
      float w = Wp[i * RR];
      a0 += h4.x * w; a1 += h4.y * w; a2 += h4.z * w; a3 += h4.w * w;
    }
    kpart[ksp][col] = make_float4(a0, a1, a2, a3);
  }
  __syncthreads();
  if (tid < 32) {
    float bb = kdb[tid];
    float4 p0 = kpart[0][tid], p1 = kpart[1][tid], p2 = kpart[2][tid], p3 = kpart[3][tid];
    kdT[tid] = make_float4(p0.x + p1.x + p2.x + p3.x + bb,
                           p0.y + p1.y + p2.y + p3.y + bb,
                           p0.z + p1.z + p2.z + p3.z + bb,
                           p0.w + p1.w + p2.w + p3.w + bb);
  }
  __syncthreads();

  // ku GEMV: 256 cols, K=32
  {
    float a0 = 0, a1 = 0, a2 = 0, a3 = 0;
    const float* Wp = kuW + tid;
#pragma unroll 8
    for (int r = 0; r < 32; r++) {
      float4 k4 = kdT[r];
      float w = Wp[r * 256];
      a0 += k4.x * w; a1 += k4.y * w; a2 += k4.z * w; a3 += k4.w * w;
    }
    float bb = kub[tid];
    bool isk = (tid & 31) < 16;
    float v0 = a0 + bb, v1 = a1 + bb, v2 = a2 + bb, v3 = a3 + bb;
    kvbuf[(n0 + 0) * 256 + tid] = isk ? elu1(v0) : v0;
    kvbuf[(n0 + 1) * 256 + tid] = isk ? elu1(v1) : v1;
    kvbuf[(n0 + 2) * 256 + tid] = isk ? elu1(v2) : v2;
    kvbuf[(n0 + 3) * 256 + tid] = isk ? elu1(v3) : v3;
  }
}

// ---------------- k_ctx: 256 blocks = 32 (b,h) x 8 T-chunks, atomic accumulate
__global__ __launch_bounds__(256) void k_ctx(const float* __restrict__ kv,
                                             float* __restrict__ ctx,
                                             float* __restrict__ ksum) {
  const int blk = blockIdx.x;
  const int bh = blk >> 3, c = blk & 7;
  const int b = bh >> 3, h = bh & 7;
  const int tid = threadIdx.x;
  const int d = tid >> 4, e = tid & 15;
  __shared__ float sh[64 * 32];
#pragma unroll
  for (int r = 0; r < 8; r++) {
    int lin = r * 256 + tid;
    int tok = lin >> 5, off = lin & 31;
    sh[lin] = kv[((b * TT + c * 64 + tok) * 256) + h * 32 + off];
  }
  __syncthreads();
  float acc = 0.f, ks = 0.f;
#pragma unroll 4
  for (int t = 0; t < 64; t++) {
    float kk = sh[t * 32 + d];
    acc += kk * sh[t * 32 + 16 + e];
    ks += kk;
  }
  atomicAdd(&ctx[bh * 256 + d * 16 + e], acc);
  if (e == 0) atomicAdd(&ksum[bh * 16 + d], ks);
}

// ---------------- k_mid: attn apply -> oW -> rot/quant -> swiglu1+res -> rms2
//                  -> gate logits -> top2 -> counts
__global__ __launch_bounds__(256) void k_mid(
    const float* __restrict__ x, const float* __restrict__ qbuf,
    const float* __restrict__ ctx, const float* __restrict__ ksum,
    const float* __restrict__ oW, const float* __restrict__ ob,
    const float* __restrict__ rot, const float* __restrict__ tqs,
    const float* __restrict__ s1W, const float* __restrict__ s1b,
    const float* __restrict__ s2W, const float* __restrict__ s2b,
    const float* __restrict__ g2, const float* __restrict__ gateW,
    const float* __restrict__ gateb,
    float* __restrict__ xnbuf, float* __restrict__ h2buf,
    float* __restrict__ gw, int* __restrict__ gidx, int* __restrict__ cnt) {
  const int tid = threadIdx.x;
  const int j = tid & 127, g = tid >> 7;
  const int lane = tid & 63, wid2 = (tid >> 6) & 1;  // wave id within g0
  const int wid4 = tid >> 6;                          // wave id among 4
  const int n0 = blockIdx.x * TPB;
  const int b = n0 >> 9;

  __shared__ float4 bufA[128], bufB[128];
  __shared__ float4 part[2][128];
  __shared__ float4 rtmp[2];
  __shared__ float wvS[4][4]; __shared__ int wiS[4][4];
  __shared__ float zS[4][4];

  // load q token-transposed (thread loads tokens 2g, 2g+1)
  {
    float a = qbuf[(n0 + 2 * g) * Dd + j];
    float c = qbuf[(n0 + 2 * g + 1) * Dd + j];
    ((float*)&bufA[j])[2 * g] = a;
    ((float*)&bufA[j])[2 * g + 1] = c;
  }
  __syncthreads();

  // attention apply -> bufB  (g0 only; 16-iter loop)
  if (g == 0) {
    int h = j >> 4, e = j & 15;
    const float* cpt = ctx + (b * NH + h) * 256;
    const float* kpt = ksum + (b * NH + h) * 16;
    float num[4] = {0, 0, 0, 0}, den[4] = {0, 0, 0, 0};
#pragma unroll
    for (int d = 0; d < 16; d++) {
      float cx = cpt[d * 16 + e], ks = kpt[d];
      float4 q4 = bufA[h * 16 + d];
      num[0] += q4.x * cx; num[1] += q4.y * cx; num[2] += q4.z * cx; num[3] += q4.w * cx;
      den[0] += q4.x * ks; den[1] += q4.y * ks; den[2] += q4.z * ks; den[3] += q4.w * ks;
    }
#pragma unroll
    for (int t = 0; t < 4; t++) ((float*)&bufB[j])[t] = num[t] / (den[t] + EPSF);
  }
  __syncthreads();

  // oW GEMV: bufB -> bufA (+ob)
  {
    float a0 = 0, a1 = 0, a2 = 0, a3 = 0;
    const float* Wp = oW + (g * 64) * Dd + j;
#pragma unroll 8
    for (int i = 0; i < 64; i++) {
      float4 h4 = bufB[g * 64 + i];
      float w = Wp[i * Dd];
      a0 += h4.x * w; a1 += h4.y * w; a2 += h4.z * w; a3 += h4.w * w;
    }
    if (g == 1) part[0][j] = make_float4(a0, a1, a2, a3);
    __syncthreads();
    if (g == 0) {
      float4 p = part[0][j];
      float bb = ob[j];
      bufA[j] = make_float4(a0 + p.x + bb, a1 + p.y + bb, a2 + p.z + bb, a3 + p.w + bb);
    }
    __syncthreads();
  }

  // rot GEMV + turbo-quant: bufA -> bufB
  {
    float a0 = 0, a1 = 0, a2 = 0, a3 = 0;
    const float* Wp = rot + (g * 64) * Dd + j;
#pragma unroll 8
    for (int i = 0; i < 64; i++) {
      float4 h4 = bufA[g * 64 + i];
      float w = Wp[i * Dd];
      a0 += h4.x * w; a1 += h4.y * w; a2 += h4.z * w; a3 += h4.w * w;
    }
    if (g == 1) part[0][j] = make_float4(a0, a1, a2, a3);
    __syncthreads();
    float tot[4];
    if (g == 0) {
      float4 p = part[0][j];
      tot[0] = a0 + p.x; tot[1] = a1 + p.y; tot[2] = a2 + p.z; tot[3] = a3 + p.w;
      float v[4];
#pragma unroll
      for (int t = 0; t < 4; t++) v[t] = tot[t] * tot[t];
#pragma unroll
      for (int o = 32; o > 0; o >>= 1) {
#pragma unroll
        for (int t = 0; t < 4; t++) v[t] += __shfl_xor(v[t], o, 64);
      }
      if (lane == 0) rtmp[wid2] = make_float4(v[0], v[1], v[2], v[3]);
    }
    __syncthreads();
    if (g == 0) {
      float scj = tqs[j];
#pragma unroll
      for (int t = 0; t < 4; t++) {
        float ss = ((const float*)&rtmp[0])[t] + ((const float*)&rtmp[1])[t];
        float mag = sqrtf(ss * (1.f / 128.f) + EPSF);
        float ph = tot[t] / mag;
        float p127 = fminf(fmaxf(ph * 127.f, -127.f), 127.f);
        ((float*)&bufB[j])[t] = (p127 * (1.f / 127.f)) * mag * scj;
      }
    }
    __syncthreads();
  }

  // s1/s2 dual GEMV: bufB -> xn (global+reg) -> rms2 -> bufA(h2T) + h2buf
  {
    float a1v[4] = {0, 0, 0, 0}, a2v[4] = {0, 0, 0, 0};
    const float* W1p = s1W + (g * 64) * Dd + j;
    const float* W2p = s2W + (g * 64) * Dd + j;
#pragma unroll 4
    for (int i = 0; i < 64; i++) {
      float4 h4 = bufB[g * 64 + i];
      float w1 = W1p[i * Dd], w2 = W2p[i * Dd];
      a1v[0] += h4.x * w1; a1v[1] += h4.y * w1; a1v[2] += h4.z * w1; a1v[3] += h4.w * w1;
      a2v[0] += h4.x * w2; a2v[1] += h4.y * w2; a2v[2] += h4.z * w2; a2v[3] += h4.w * w2;
    }
    if (g == 1) {
      part[0][j] = make_float4(a1v[0], a1v[1], a1v[2], a1v[3]);
      part[1][j] = make_float4(a2v[0], a2v[1], a2v[2], a2v[3]);
    }
    __syncthreads();
    float xn[4];
    if (g == 0) {
      float b1 = s1b[j], b2 = s2b[j];
      float4 p1 = part[0][j], p2 = part[1][j];
      float gv[4], uv[4];
      gv[0] = a1v[0] + p1.x + b1; gv[1] = a1v[1] + p1.y + b1;
      gv[2] = a1v[2] + p1.z + b1; gv[3] = a1v[3] + p1.w + b1;
      uv[0] = a2v[0] + p2.x + b2; uv[1] = a2v[1] + p2.y + b2;
      uv[2] = a2v[2] + p2.z + b2; uv[3] = a2v[3] + p2.w + b2;
      float v[4];
#pragma unroll
      for (int t = 0; t < 4; t++) {
        xn[t] = x[(n0 + t) * Dd + j] + gv[t] * sigm(gv[t]) * uv[t];
        xnbuf[(n0 + t) * Dd + j] = xn[t];
        v[t] = xn[t] * xn[t];
      }
#pragma unroll
      for (int o = 32; o > 0; o >>= 1) {
#pragma unroll
        for (int t = 0; t < 4; t++) v[t] += __shfl_xor(v[t], o, 64);
      }
      if (lane == 0) rtmp[wid2] = make_float4(v[0], v[1], v[2], v[3]);
    }
    __syncthreads();
    if (g == 0) {
      float g2j = g2[j];
#pragma unroll
      for (int t = 0; t < 4; t++) {
        float ss = ((const float*)&rtmp[0])[t] + ((const float*)&rtmp[1])[t];
        float h2v = g2j * xn[t] * rsqrtf(ss * (1.f / 128.f) + EPSF);
        ((float*)&bufA[j])[t] = h2v;
        h2buf[(n0 + t) * Dd + j] = h2v;
      }
    }
    __syncthreads();
  }

  // gate logits: all 256 threads, col = tid, K=128 on bufA
  float val[4];
  {
    float a0 = 0, a1 = 0, a2 = 0, a3 = 0;
    const float* Wp = gateW + tid;
#pragma unroll 8
    for (int i = 0; i < 128; i++) {
      float4 h4 = bufA[i];
      float w = Wp[i * NE];
      a0 += h4.x * w; a1 += h4.y * w; a2 += h4.z * w; a3 += h4.w * w;
    }
    float bb = gateb[tid];
    val[0] = a0 + bb; val[1] = a1 + bb; val[2] = a2 + bb; val[3] = a3 + bb;
  }

  // top-2 over 256 cols (4 waves)
  float m1[4]; int i1[4];
  {
    float bv[4]; int bi[4];
#pragma unroll
    for (int t = 0; t < 4; t++) { bv[t] = val[t]; bi[t] = tid; }
#pragma unroll
    for (int o = 32; o > 0; o >>= 1) {
#pragma unroll
      for (int t = 0; t < 4; t++) {
        float wv = __shfl_xor(bv[t], o, 64);
        int wi = __shfl_xor(bi[t], o, 64);
        if (wv > bv[t] || (wv == bv[t] && wi < bi[t])) { bv[t] = wv; bi[t] = wi; }
      }
    }
    if (lane == 0) {
#pragma unroll
      for (int t = 0; t < 4; t++) { wvS[wid4][t] = bv[t]; wiS[wid4][t] = bi[t]; }
    }
    __syncthreads();
#pragma unroll
    for (int t = 0; t < 4; t++) {
      m1[t] = wvS[0][t]; i1[t] = wiS[0][t];
#pragma unroll
      for (int w = 1; w < 4; w++) {
        float cv = wvS[w][t]; int ci = wiS[w][t];
        if (cv > m1[t] || (cv == m1[t] && ci < i1[t])) { m1[t] = cv; i1[t] = ci; }
      }
    }
    __syncthreads();
  }
  float m2[4]; int i2[4];
  {
    float bv[4]; int bi[4];
#pragma unroll
    for (int t = 0; t < 4; t++) {
      bv[t] = (tid == i1[t]) ? -INFINITY : val[t];
      bi[t] = tid;
    }
#pragma unroll
    for (int o = 32; o > 0; o >>= 1) {
#pragma unroll
      for (int t = 0; t < 4; t++) {
        float wv = __shfl_xor(bv[t], o, 64);
        int wi = __shfl_xor(bi[t], o, 64);
        if (wv > bv[t] || (wv == bv[t] && wi < bi[t])) { bv[t] = wv; bi[t] = wi; }
      }
    }
    if (lane == 0) {
#pragma unroll
      for (int t = 0; t < 4; t++) { wvS[wid4][t] = bv[t]; wiS[wid4][t] = bi[t]; }
    }
    __syncthreads();
#pragma unroll
    for (int t = 0; t < 4; t++) {
      m2[t] = wvS[0][t]; i2[t] = wiS[0][t];
#pragma unroll
      for (int w = 1; w < 4; w++) {
        float cv = wvS[w][t]; int ci = wiS[w][t];
        if (cv > m2[t] || (cv == m2[t] && ci < i2[t])) { m2[t] = cv; i2[t] = ci; }
      }
    }
    __syncthreads();
  }
  // softmax denominator
  {
    float v[4];
#pragma unroll
    for (int t = 0; t < 4; t++) v[t] = expf(val[t] - m1[t]);
#pragma unroll
    for (int o = 32; o > 0; o >>= 1) {
#pragma unroll
      for (int t = 0; t < 4; t++) v[t] += __shfl_xor(v[t], o, 64);
    }
    if (lane == 0) {
#pragma unroll
      for (int t = 0; t < 4; t++) zS[wid4][t] = v[t];
    }
    __syncthreads();
  }
  if (tid < 4) {
    int t = tid;
    float Z = zS[0][t] + zS[1][t] + zS[2][t] + zS[3][t];
    float p1 = 1.f / Z;
    float p2 = expf(m2[t] - m1[t]) / Z;
    float s = p1 + p2 + EPSF;
    gidx[(n0 + t) * 2 + 0] = i1[t];
    gidx[(n0 + t) * 2 + 1] = i2[t];
    gw[(n0 + t) * 2 + 0] = p1 / s;
    gw[(n0 + t) * 2 + 1] = p2 / s;
    atomicAdd(&cnt[i1[t]], 1);
    atomicAdd(&cnt[i2[t]], 1);
  }
}

// ---------------- k_route: 1 block: prefix-sum counts + scatter assignments
__global__ __launch_bounds__(256) void k_route(const int* __restrict__ cnt,
                                               const int* __restrict__ gidx,
                                               int* __restrict__ offb,
                                               int* __restrict__ slottok,
                                               int* __restrict__ tokslot) {
  const int tid = threadIdx.x;
  __shared__ int sc[256];
  __shared__ int lcur[256];
  int c = cnt[tid];
  sc[tid] = c;
  __syncthreads();
  for (int o = 1; o < 256; o <<= 1) {
    int a = (tid >= o) ? sc[tid - o] : 0;
    __syncthreads();
    sc[tid] += a;
    __syncthreads();
  }
  int excl = sc[tid] - c;
  offb[tid] = excl;
  lcur[tid] = excl;
  __syncthreads();
  for (int base = 0; base < NTOK; base += 256) {
    int tok = base + tid;
    int e1 = gidx[tok * 2], e2 = gidx[tok * 2 + 1];
    int s1 = atomicAdd(&lcur[e1], 1);
    tokslot[tok * 2] = s1; slottok[s1] = tok;
    int s2 = atomicAdd(&lcur[e2], 1);
    tokslot[tok * 2 + 1] = s2; slottok[s2] = tok;
  }
}

// ---------------- k_exp: one block per expert; W read once; tiles of 16 tokens
__global__ __launch_bounds__(256) void k_exp(const float* __restrict__ h2buf,
                                             const int* __restrict__ slottok,
                                             const int* __restrict__ cnt,
                                             const int* __restrict__ offb,
                                             const float* __restrict__ expW,
                                             float* __restrict__ ybuf) {
  const int e = blockIdx.x;
  const int n = cnt[e];
  if (n == 0) return;
  const int base = offb[e];
  const int tid = threadIdx.x;
  const int j = tid & 127, g = tid >> 7;   // g: token half (8 tokens each)
  __shared__ __align__(16) float hT[128][16];
  const float* Wp = expW + (size_t)e * Dd * Dd + j;
  for (int t0 = 0; t0 < n; t0 += 16) {
    int m = n - t0; if (m > 16) m = 16;
    __syncthreads();
    for (int tt = g; tt < m; tt += 2) {
      int tok = slottok[base + t0 + tt];
      hT[j][tt] = h2buf[tok * Dd + j];
    }
    __syncthreads();
    float acc[8] = {0, 0, 0, 0, 0, 0, 0, 0};
#pragma unroll 4
    for (int i = 0; i < 128; i++) {
      float w = Wp[i * Dd];
      const float* hp = &hT[i][g * 8];
      float4 A = *(const float4*)(hp);
      float4 B = *(const float4*)(hp + 4);
      acc[0] += A.x * w; acc[1] += A.y * w; acc[2] += A.z * w; acc[3] += A.w * w;
      acc[4] += B.x * w; acc[5] += B.y * w; acc[6] += B.z * w; acc[7] += B.w * w;
    }
#pragma unroll
    for (int k = 0; k < 8; k++) {
      int tt = g * 8 + k;
      if (tt < m) ybuf[(size_t)(base + t0 + tt) * Dd + j] = acc[k];
    }
  }
}

// ---------------- k_post: wavg -> m-swiglu -> out residual; wvar -> consensus
__global__ __launch_bounds__(256) void k_post(
    const float* __restrict__ xnbuf, const float* __restrict__ ybuf,
    const int* __restrict__ tokslot, const float* __restrict__ gw,
    const float* __restrict__ m1W, const float* __restrict__ m1b,
    const float* __restrict__ m2W, const float* __restrict__ m2b,
    float* __restrict__ out) {
  const int tid = threadIdx.x;
  const int j = tid & 127, g = tid >> 7;
  const int lane = tid & 63, wid2 = (tid >> 6) & 1;
  const int n0 = blockIdx.x * TPB;

  __shared__ float4 y1T[128], y2T[128], inT[128], sT[128];
  __shared__ float4 part[2][128];
  __shared__ float4 rtmp[2];
  __shared__ int sSlot[4][2];
  __shared__ float sWt[4][2];

  if (tid < 4) {
    sSlot[tid][0] = tokslot[(n0 + tid) * 2];
    sSlot[tid][1] = tokslot[(n0 + tid) * 2 + 1];
    sWt[tid][0] = gw[(n0 + tid) * 2];
    sWt[tid][1] = gw[(n0 + tid) * 2 + 1];
  }
  __syncthreads();

#pragma unroll
  for (int tt = 0; tt < 2; tt++) {
    int t = 2 * g + tt;
    float y1 = ybuf[(size_t)sSlot[t][0] * Dd + j];
    float y2 = ybuf[(size_t)sSlot[t][1] * Dd + j];
    ((float*)&y1T[j])[t] = y1;
    ((float*)&y2T[j])[t] = y2;
    ((float*)&inT[j])[t] = sWt[t][0] * y1 + sWt[t][1] * y2;
  }
  __syncthreads();

  // m1/m2 dual GEMV on inT; epilogue: swiglu -> sT, out = xn + s
  {
    float a1v[4] = {0, 0, 0, 0}, a2v[4] = {0, 0, 0, 0};
    const float* W1p = m1W + (g * 64) * Dd + j;
    const float* W2p = m2W + (g * 64) * Dd + j;
#pragma unroll 4
    for (int i = 0; i < 64; i++) {
      float4 h4 = inT[g * 64 + i];
      float w1 = W1p[i * Dd], w2 = W2p[i * Dd];
      a1v[0] += h4.x * w1; a1v[1] += h4.y * w1; a1v[2] += h4.z * w1; a1v[3] += h4.w * w1;
      a2v[0] += h4.x * w2; a2v[1] += h4.y * w2; a2v[2] += h4.z * w2; a2v[3] += h4.w * w2;
    }
    if (g == 1) {
      part[0][j] = make_float4(a1v[0], a1v[1], a1v[2], a1v[3]);
      part[1][j] = make_float4(a2v[0], a2v[1], a2v[2], a2v[3]);
    }
    __syncthreads();
    if (g == 0) {
      float b1 = m1b[j], b2 = m2b[j];
      float4 p1 = part[0][j], p2 = part[1][j];
      float gv[4], uv[4];
      gv[0] = a1v[0] + p1.x + b1; gv[1] = a1v[1] + p1.y + b1;
      gv[2] = a1v[2] + p1.z + b1; gv[3] = a1v[3] + p1.w + b1;
      uv[0] = a2v[0] + p2.x + b2; uv[1] = a2v[1] + p2.y + b2;
      uv[2] = a2v[2] + p2.z + b2; uv[3] = a2v[3] + p2.w + b2;
#pragma unroll
      for (int t = 0; t < 4; t++) {
        float sv = gv[t] * sigm(gv[t]) * uv[t];
        ((float*)&sT[j])[t] = sv;
        out[(n0 + t) * Dd + j] = xnbuf[(n0 + t) * Dd + j] + sv;
      }
    }
    __syncthreads();
  }

  // wvar + consensus
  if (g == 0) {
    float v[4];
#pragma unroll
    for (int t = 0; t < 4; t++) {
      float sv = ((const float*)&sT[j])[t];
      float d1 = ((const float*)&y1T[j])[t] - sv;
      float d2 = ((const float*)&y2T[j])[t] - sv;
      v[t] = sWt[t][0] * d1 * d1 + sWt[t][1] * d2 * d2;
    }
#pragma unroll
    for (int o = 32; o > 0; o >>= 1) {
#pragma unroll
      for (int t = 0; t < 4; t++) v[t] += __shfl_xor(v[t], o, 64);
    }
    if (lane == 0) rtmp[wid2] = make_float4(v[0], v[1], v[2], v[3]);
  }
  __syncthreads();
  if (tid < 4) {
    float s = ((const float*)&rtmp[0])[tid] + ((const float*)&rtmp[1])[tid];
    out[NTOK * Dd + n0 + tid] = expf(-s * (1.f / 128.f));
  }
}

extern "C" void kernel_launch(void* const* d_in, const int* in_sizes, int n_in,
                              void* d_out, int out_size, void* d_ws, size_t ws_size,
                              hipStream_t stream) {
  const float* x   = (const float*)d_in[0];
  const float* g1  = (const float*)d_in[1];
  const float* qW  = (const float*)d_in[2];
  const float* qb  = (const float*)d_in[3];
  const float* kdW = (const float*)d_in[4];
  const float* kdb = (const float*)d_in[5];
  const float* kuW = (const float*)d_in[6];
  const float* kub = (const float*)d_in[7];
  const float* oW  = (const float*)d_in[8];
  const float* ob  = (const float*)d_in[9];
  const float* rot = (const float*)d_in[10];
  const float* tqs = (const float*)d_in[11];
  const float* s1W = (const float*)d_in[12];
  const float* s1b = (const float*)d_in[13];
  const float* s2W = (const float*)d_in[14];
  const float* s2b = (const float*)d_in[15];
  const float* g2  = (const float*)d_in[16];
  const float* gW  = (const float*)d_in[17];
  const float* gb  = (const float*)d_in[18];
  const float* eW  = (const float*)d_in[19];
  const float* m1W = (const float*)d_in[20];
  const float* m1b = (const float*)d_in[21];
  const float* m2W = (const float*)d_in[22];
  const float* m2b = (const float*)d_in[23];
  float* out = (float*)d_out;
  float* ws  = (float*)d_ws;

  // layout (floats). Region A (qbuf|kvbuf) is dead after k_mid/k_ctx and is
  // reused as ybuf by k_exp/k_post.
  float* qbuf  = ws;                       // 262144
  float* kvbuf = ws + 262144;              // 524288
  float* ybuf  = ws;                       // 524288 (aliases qbuf+kvbuf, safe)
  float* ctx   = ws + 786432;              // 8192
  float* ksum  = ctx + 8192;               // 512
  float* h2buf = ksum + 512;               // 262144
  float* xnbuf = h2buf + 262144;           // 262144
  float* gw    = xnbuf + 262144;           // 4096
  int*   gidx    = (int*)(gw + 4096);      // 4096
  int*   cnt     = gidx + 4096;            // 256
  int*   offb    = cnt + 256;              // 256
  int*   slottok = offb + 256;             // 4096
  int*   tokslot = slottok + 4096;         // 4096

  k_pre<<<NTOK / TPB, 256, 0, stream>>>(x, g1, qW, qb, kdW, kdb, kuW, kub,
                                        qbuf, kvbuf, ctx, ksum, cnt);
  k_ctx<<<256, 256, 0, stream>>>(kvbuf, ctx, ksum);
  k_mid<<<NTOK / TPB, 256, 0, stream>>>(x, qbuf, ctx, ksum, oW, ob, rot, tqs,
                                        s1W, s1b, s2W, s2b, g2, gW, gb,
                                        xnbuf, h2buf, gw, gidx, cnt);
  k_route<<<1, 256, 0, stream>>>(cnt, gidx, offb, slottok, tokslot);
  k_exp<<<NE, 256, 0, stream>>>(h2buf, slottok, cnt, offb, eW, ybuf);
  k_post<<<NTOK / TPB, 256, 0, stream>>>(xnbuf, ybuf, tokslot, gw,
                                         m1W, m1b, m2W, m2b, out);
}

// Round 3
// 172.101 us; speedup vs baseline: 1.1891x; 1.1360x over previous
//
#include <hip/hip_runtime.h>
#include <hip/hip_bf16.h>
#include <math.h>

static constexpr int Dd   = 128;
static constexpr int NH   = 8;
static constexpr int HD   = 16;
static constexpr int NE   = 256;
static constexpr int RR   = 32;
static constexpr int BB   = 4;
static constexpr int TT   = 512;
static constexpr int NTOK = BB * TT;   // 2048
static constexpr int TPB  = 4;
#define EPSF 1e-6f

__device__ __forceinline__ float elu1(float v) { return v > 0.f ? v + 1.f : expf(v); }
__device__ __forceinline__ float sigm(float v) { return 1.f / (1.f + expf(-v)); }

// ================= k_pre: rmsnorm1 + q(+elu) + kd + ku(+elu on k half) ======
// 512 threads: j=tid&127 (col), g=tid>>7 (K-quarter)
__global__ __launch_bounds__(512) void k_pre(
    const float* __restrict__ x, const float* __restrict__ g1,
    const float* __restrict__ qW, const float* __restrict__ qb,
    const float* __restrict__ kdW, const float* __restrict__ kdb,
    const float* __restrict__ kuW, const float* __restrict__ kub,
    float* __restrict__ qbuf, float* __restrict__ kvbuf,
    float* __restrict__ ctx, float* __restrict__ ksum, int* __restrict__ cnt) {
  const int tid = threadIdx.x;
  const int j = tid & 127, g = tid >> 7;
  const int lane = tid & 63;
  const int n0 = blockIdx.x * TPB;

  __shared__ float4 h1T[128];
  __shared__ float4 part[3][128];
  __shared__ float4 kpart[8][32];
  __shared__ float4 kdT[32];
  __shared__ float4 kupart[256];
  __shared__ float4 rtmp[2];

  if (blockIdx.x == 0) {  // zero accumulators for later kernels
    for (int i = tid; i < 32 * 256; i += 512) ctx[i] = 0.f;
    ksum[tid] = 0.f;                     // 512 floats exactly
    if (tid < 256) cnt[tid] = 0;
  }

  // rmsnorm1 (2 waves compute; others pass barriers)
  float xv[4];
  if (tid < 128) {
    float v[4];
#pragma unroll
    for (int t = 0; t < 4; t++) { xv[t] = x[(n0 + t) * Dd + j]; v[t] = xv[t] * xv[t]; }
#pragma unroll
    for (int o = 32; o > 0; o >>= 1) {
#pragma unroll
      for (int t = 0; t < 4; t++) v[t] += __shfl_xor(v[t], o, 64);
    }
    if (lane == 0) rtmp[tid >> 6] = make_float4(v[0], v[1], v[2], v[3]);
  }
  __syncthreads();
  if (tid < 128) {
    float g1j = g1[j];
#pragma unroll
    for (int t = 0; t < 4; t++) {
      float ss = ((const float*)&rtmp[0])[t] + ((const float*)&rtmp[1])[t];
      ((float*)&h1T[j])[t] = g1j * xv[t] * rsqrtf(ss * (1.f / 128.f) + EPSF);
    }
  }
  __syncthreads();

  // q GEMV, K-split-4
  {
    float a0 = 0, a1 = 0, a2 = 0, a3 = 0;
    const float* Wp = qW + (g * 32) * Dd + j;
#pragma unroll 16
    for (int i = 0; i < 32; i++) {
      float4 h4 = h1T[g * 32 + i];
      float w = Wp[i * Dd];
      a0 += h4.x * w; a1 += h4.y * w; a2 += h4.z * w; a3 += h4.w * w;
    }
    if (g) part[g - 1][j] = make_float4(a0, a1, a2, a3);
    __syncthreads();
    if (g == 0) {
      float4 p0 = part[0][j], p1 = part[1][j], p2 = part[2][j];
      float bb = qb[j];
      qbuf[(n0 + 0) * Dd + j] = elu1(a0 + p0.x + p1.x + p2.x + bb);
      qbuf[(n0 + 1) * Dd + j] = elu1(a1 + p0.y + p1.y + p2.y + bb);
      qbuf[(n0 + 2) * Dd + j] = elu1(a2 + p0.z + p1.z + p2.z + bb);
      qbuf[(n0 + 3) * Dd + j] = elu1(a3 + p0.w + p1.w + p2.w + bb);
    }
    __syncthreads();
  }

  // kd GEMV: 32 cols x 8 K-splits (tid<256)
  if (tid < 256) {
    int col = tid & 31, ksp = tid >> 5;
    float a0 = 0, a1 = 0, a2 = 0, a3 = 0;
    const float* Wp = kdW + (ksp * 16) * RR + col;
#pragma unroll
    for (int i = 0; i < 16; i++) {
      float4 h4 = h1T[ksp * 16 + i];
      float w = Wp[i * RR];
      a0 += h4.x * w; a1 += h4.y * w; a2 += h4.z * w; a3 += h4.w * w;
    }
    kpart[ksp][col] = make_float4(a0, a1, a2, a3);
  }
  __syncthreads();
  if (tid < 32) {
    float bb = kdb[tid];
    float s0 = bb, s1 = bb, s2 = bb, s3 = bb;
#pragma unroll
    for (int k = 0; k < 8; k++) {
      float4 p = kpart[k][tid];
      s0 += p.x; s1 += p.y; s2 += p.z; s3 += p.w;
    }
    kdT[tid] = make_float4(s0, s1, s2, s3);
  }
  __syncthreads();

  // ku GEMV: 256 cols, K=32 split 2
  {
    int col = tid & 255, kh = tid >> 8;
    float a0 = 0, a1 = 0, a2 = 0, a3 = 0;
    const float* Wp = kuW + (kh * 16) * 256 + col;
#pragma unroll
    for (int r = 0; r < 16; r++) {
      float4 k4 = kdT[kh * 16 + r];
      float w = Wp[r * 256];
      a0 += k4.x * w; a1 += k4.y * w; a2 += k4.z * w; a3 += k4.w * w;
    }
    if (kh) kupart[col] = make_float4(a0, a1, a2, a3);
    __syncthreads();
    if (!kh) {
      float4 p = kupart[col];
      float bb = kub[col];
      bool isk = (col & 31) < 16;
      float v0 = a0 + p.x + bb, v1 = a1 + p.y + bb, v2 = a2 + p.z + bb, v3 = a3 + p.w + bb;
      kvbuf[(n0 + 0) * 256 + col] = isk ? elu1(v0) : v0;
      kvbuf[(n0 + 1) * 256 + col] = isk ? elu1(v1) : v1;
      kvbuf[(n0 + 2) * 256 + col] = isk ? elu1(v2) : v2;
      kvbuf[(n0 + 3) * 256 + col] = isk ? elu1(v3) : v3;
    }
  }
}

// ================= k_ctx: 256 blocks = 32 (b,h) x 8 T-chunks ================
__global__ __launch_bounds__(256) void k_ctx(const float* __restrict__ kv,
                                             float* __restrict__ ctx,
                                             float* __restrict__ ksum) {
  const int blk = blockIdx.x;
  const int bh = blk >> 3, c = blk & 7;
  const int b = bh >> 3, h = bh & 7;
  const int tid = threadIdx.x;
  const int d = tid >> 4, e = tid & 15;
  __shared__ float sh[64 * 32];
#pragma unroll
  for (int r = 0; r < 8; r++) {
    int lin = r * 256 + tid;
    int tok = lin >> 5, off = lin & 31;
    sh[lin] = kv[((b * TT + c * 64 + tok) * 256) + h * 32 + off];
  }
  __syncthreads();
  float acc = 0.f, ks = 0.f;
#pragma unroll 4
  for (int t = 0; t < 64; t++) {
    float kk = sh[t * 32 + d];
    acc += kk * sh[t * 32 + 16 + e];
    ks += kk;
  }
  atomicAdd(&ctx[bh * 256 + d * 16 + e], acc);
  if (e == 0) atomicAdd(&ksum[bh * 16 + d], ks);
}

// ================= k_mid ====================================================
__global__ __launch_bounds__(512) void k_mid(
    const float* __restrict__ x, const float* __restrict__ qbuf,
    const float* __restrict__ ctx, const float* __restrict__ ksum,
    const float* __restrict__ oW, const float* __restrict__ ob,
    const float* __restrict__ rot, const float* __restrict__ tqs,
    const float* __restrict__ s1W, const float* __restrict__ s1b,
    const float* __restrict__ s2W, const float* __restrict__ s2b,
    const float* __restrict__ g2, const float* __restrict__ gateW,
    const float* __restrict__ gateb,
    float* __restrict__ xnbuf, float* __restrict__ h2buf,
    float* __restrict__ gw, int* __restrict__ gidx, int* __restrict__ cnt) {
  const int tid = threadIdx.x;
  const int j = tid & 127, g = tid >> 7;
  const int lane = tid & 63;
  const int n0 = blockIdx.x * TPB;
  const int b = n0 >> 9;

  __shared__ float4 bufA[128], bufB[128];
  __shared__ float4 part[3][128];
  __shared__ float4 gpart[256];
  __shared__ float4 rtmp[2];
  __shared__ float wvS[4][4]; __shared__ int wiS[4][4];
  __shared__ float zS[4][4];

  // load q token-transposed: thread (j,g) loads token g
  ((float*)&bufA[j])[g] = qbuf[(n0 + g) * Dd + j];
  __syncthreads();

  // attention apply -> bufB  (tid<128)
  if (tid < 128) {
    int h = j >> 4, e = j & 15;
    const float* cpt = ctx + (b * NH + h) * 256;
    const float* kpt = ksum + (b * NH + h) * 16;
    float num[4] = {0, 0, 0, 0}, den[4] = {0, 0, 0, 0};
#pragma unroll
    for (int d = 0; d < 16; d++) {
      float cx = cpt[d * 16 + e], ks = kpt[d];
      float4 q4 = bufA[h * 16 + d];
      num[0] += q4.x * cx; num[1] += q4.y * cx; num[2] += q4.z * cx; num[3] += q4.w * cx;
      den[0] += q4.x * ks; den[1] += q4.y * ks; den[2] += q4.z * ks; den[3] += q4.w * ks;
    }
#pragma unroll
    for (int t = 0; t < 4; t++) ((float*)&bufB[j])[t] = num[t] / (den[t] + EPSF);
  }
  __syncthreads();

  // oW GEMV (K-split-4): bufB -> bufA (+ob)
  {
    float a0 = 0, a1 = 0, a2 = 0, a3 = 0;
    const float* Wp = oW + (g * 32) * Dd + j;
#pragma unroll 16
    for (int i = 0; i < 32; i++) {
      float4 h4 = bufB[g * 32 + i];
      float w = Wp[i * Dd];
      a0 += h4.x * w; a1 += h4.y * w; a2 += h4.z * w; a3 += h4.w * w;
    }
    if (g) part[g - 1][j] = make_float4(a0, a1, a2, a3);
    __syncthreads();
    if (g == 0) {
      float4 p0 = part[0][j], p1 = part[1][j], p2 = part[2][j];
      float bb = ob[j];
      bufA[j] = make_float4(a0 + p0.x + p1.x + p2.x + bb, a1 + p0.y + p1.y + p2.y + bb,
                            a2 + p0.z + p1.z + p2.z + bb, a3 + p0.w + p1.w + p2.w + bb);
    }
    __syncthreads();
  }

  // rot GEMV + turbo-quant: bufA -> bufB
  {
    float a0 = 0, a1 = 0, a2 = 0, a3 = 0;
    const float* Wp = rot + (g * 32) * Dd + j;
#pragma unroll 16
    for (int i = 0; i < 32; i++) {
      float4 h4 = bufA[g * 32 + i];
      float w = Wp[i * Dd];
      a0 += h4.x * w; a1 += h4.y * w; a2 += h4.z * w; a3 += h4.w * w;
    }
    if (g) part[g - 1][j] = make_float4(a0, a1, a2, a3);
    __syncthreads();
    float tot[4];
    if (g == 0) {
      float4 p0 = part[0][j], p1 = part[1][j], p2 = part[2][j];
      tot[0] = a0 + p0.x + p1.x + p2.x; tot[1] = a1 + p0.y + p1.y + p2.y;
      tot[2] = a2 + p0.z + p1.z + p2.z; tot[3] = a3 + p0.w + p1.w + p2.w;
      float v[4];
#pragma unroll
      for (int t = 0; t < 4; t++) v[t] = tot[t] * tot[t];
#pragma unroll
      for (int o = 32; o > 0; o >>= 1) {
#pragma unroll
        for (int t = 0; t < 4; t++) v[t] += __shfl_xor(v[t], o, 64);
      }
      if (lane == 0) rtmp[tid >> 6] = make_float4(v[0], v[1], v[2], v[3]);
    }
    __syncthreads();
    if (g == 0) {
      float scj = tqs[j];
#pragma unroll
      for (int t = 0; t < 4; t++) {
        float ss = ((const float*)&rtmp[0])[t] + ((const float*)&rtmp[1])[t];
        float mag = sqrtf(ss * (1.f / 128.f) + EPSF);
        float ph = tot[t] / mag;
        float p127 = fminf(fmaxf(ph * 127.f, -127.f), 127.f);
        ((float*)&bufB[j])[t] = (p127 * (1.f / 127.f)) * mag * scj;
      }
    }
    __syncthreads();
  }

  // s1/s2 dual GEMV (g0,g1: s1W halves; g2,g3: s2W halves): bufB -> xn -> rms2
  {
    float a0 = 0, a1 = 0, a2 = 0, a3 = 0;
    const float* Wp = (g < 2 ? s1W : s2W) + ((g & 1) * 64) * Dd + j;
#pragma unroll 16
    for (int i = 0; i < 64; i++) {
      float4 h4 = bufB[(g & 1) * 64 + i];
      float w = Wp[i * Dd];
      a0 += h4.x * w; a1 += h4.y * w; a2 += h4.z * w; a3 += h4.w * w;
    }
    if (g) part[g - 1][j] = make_float4(a0, a1, a2, a3);
    __syncthreads();
    float xn[4];
    if (g == 0) {
      float b1 = s1b[j], b2 = s2b[j];
      float4 p0 = part[0][j], p1 = part[1][j], p2 = part[2][j];
      float gv[4], uv[4];
      gv[0] = a0 + p0.x + b1; gv[1] = a1 + p0.y + b1;
      gv[2] = a2 + p0.z + b1; gv[3] = a3 + p0.w + b1;
      uv[0] = p1.x + p2.x + b2; uv[1] = p1.y + p2.y + b2;
      uv[2] = p1.z + p2.z + b2; uv[3] = p1.w + p2.w + b2;
      float v[4];
#pragma unroll
      for (int t = 0; t < 4; t++) {
        xn[t] = x[(n0 + t) * Dd + j] + gv[t] * sigm(gv[t]) * uv[t];
        xnbuf[(n0 + t) * Dd + j] = xn[t];
        v[t] = xn[t] * xn[t];
      }
#pragma unroll
      for (int o = 32; o > 0; o >>= 1) {
#pragma unroll
        for (int t = 0; t < 4; t++) v[t] += __shfl_xor(v[t], o, 64);
      }
      if (lane == 0) rtmp[tid >> 6] = make_float4(v[0], v[1], v[2], v[3]);
    }
    __syncthreads();
    if (g == 0) {
      float g2j = g2[j];
#pragma unroll
      for (int t = 0; t < 4; t++) {
        float ss = ((const float*)&rtmp[0])[t] + ((const float*)&rtmp[1])[t];
        float h2v = g2j * xn[t] * rsqrtf(ss * (1.f / 128.f) + EPSF);
        ((float*)&bufA[j])[t] = h2v;
        h2buf[(n0 + t) * Dd + j] = h2v;
      }
    }
    __syncthreads();
  }

  // gate logits: col=tid&255, K-split-2 on bufA
  float val[4];
  {
    int col = tid & 255, kh = tid >> 8;
    float a0 = 0, a1 = 0, a2 = 0, a3 = 0;
    const float* Wp = gateW + (kh * 64) * NE + col;
#pragma unroll 16
    for (int i = 0; i < 64; i++) {
      float4 h4 = bufA[kh * 64 + i];
      float w = Wp[i * NE];
      a0 += h4.x * w; a1 += h4.y * w; a2 += h4.z * w; a3 += h4.w * w;
    }
    if (kh) gpart[col] = make_float4(a0, a1, a2, a3);
    __syncthreads();
    if (!kh) {
      float4 p = gpart[col];
      float bb = gateb[col];
      val[0] = a0 + p.x + bb; val[1] = a1 + p.y + bb;
      val[2] = a2 + p.z + bb; val[3] = a3 + p.w + bb;
    }
  }
  __syncthreads();

  // top-2 over 256 cols held by tid<256 (4 waves)
  float m1[4]; int i1[4];
  {
    if (tid < 256) {
      float bv[4]; int bi[4];
#pragma unroll
      for (int t = 0; t < 4; t++) { bv[t] = val[t]; bi[t] = tid; }
#pragma unroll
      for (int o = 32; o > 0; o >>= 1) {
#pragma unroll
        for (int t = 0; t < 4; t++) {
          float wv = __shfl_xor(bv[t], o, 64);
          int wi = __shfl_xor(bi[t], o, 64);
          if (wv > bv[t] || (wv == bv[t] && wi < bi[t])) { bv[t] = wv; bi[t] = wi; }
        }
      }
      if (lane == 0) {
#pragma unroll
        for (int t = 0; t < 4; t++) { wvS[tid >> 6][t] = bv[t]; wiS[tid >> 6][t] = bi[t]; }
      }
    }
    __syncthreads();
    if (tid < 256) {
#pragma unroll
      for (int t = 0; t < 4; t++) {
        m1[t] = wvS[0][t]; i1[t] = wiS[0][t];
#pragma unroll
        for (int w = 1; w < 4; w++) {
          float cv = wvS[w][t]; int ci = wiS[w][t];
          if (cv > m1[t] || (cv == m1[t] && ci < i1[t])) { m1[t] = cv; i1[t] = ci; }
        }
      }
    }
    __syncthreads();
  }
  float m2[4]; int i2[4];
  {
    if (tid < 256) {
      float bv[4]; int bi[4];
#pragma unroll
      for (int t = 0; t < 4; t++) {
        bv[t] = (tid == i1[t]) ? -INFINITY : val[t];
        bi[t] = tid;
      }
#pragma unroll
      for (int o = 32; o > 0; o >>= 1) {
#pragma unroll
        for (int t = 0; t < 4; t++) {
          float wv = __shfl_xor(bv[t], o, 64);
          int wi = __shfl_xor(bi[t], o, 64);
          if (wv > bv[t] || (wv == bv[t] && wi < bi[t])) { bv[t] = wv; bi[t] = wi; }
        }
      }
      if (lane == 0) {
#pragma unroll
        for (int t = 0; t < 4; t++) { wvS[tid >> 6][t] = bv[t]; wiS[tid >> 6][t] = bi[t]; }
      }
    }
    __syncthreads();
    if (tid < 256) {
#pragma unroll
      for (int t = 0; t < 4; t++) {
        m2[t] = wvS[0][t]; i2[t] = wiS[0][t];
#pragma unroll
        for (int w = 1; w < 4; w++) {
          float cv = wvS[w][t]; int ci = wiS[w][t];
          if (cv > m2[t] || (cv == m2[t] && ci < i2[t])) { m2[t] = cv; i2[t] = ci; }
        }
      }
    }
    __syncthreads();
  }
  // softmax denominator over 256 logits
  {
    if (tid < 256) {
      float v[4];
#pragma unroll
      for (int t = 0; t < 4; t++) v[t] = expf(val[t] - m1[t]);
#pragma unroll
      for (int o = 32; o > 0; o >>= 1) {
#pragma unroll
        for (int t = 0; t < 4; t++) v[t] += __shfl_xor(v[t], o, 64);
      }
      if (lane == 0) {
#pragma unroll
        for (int t = 0; t < 4; t++) zS[tid >> 6][t] = v[t];
      }
    }
    __syncthreads();
  }
  if (tid < 4) {
    int t = tid;
    float Z = zS[0][t] + zS[1][t] + zS[2][t] + zS[3][t];
    float p1 = 1.f / Z;
    float p2 = expf(m2[t] - m1[t]) / Z;
    float s = p1 + p2 + EPSF;
    gidx[(n0 + t) * 2 + 0] = i1[t];
    gidx[(n0 + t) * 2 + 1] = i2[t];
    gw[(n0 + t) * 2 + 0] = p1 / s;
    gw[(n0 + t) * 2 + 1] = p2 / s;
    atomicAdd(&cnt[i1[t]], 1);
    atomicAdd(&cnt[i2[t]], 1);
  }
}

// ================= k_route ==================================================
__global__ __launch_bounds__(256) void k_route(const int* __restrict__ cnt,
                                               const int* __restrict__ gidx,
                                               int* __restrict__ offb,
                                               int* __restrict__ slottok,
                                               int* __restrict__ tokslot) {
  const int tid = threadIdx.x;
  __shared__ int sc[256];
  __shared__ int lcur[256];
  int c = cnt[tid];
  sc[tid] = c;
  __syncthreads();
  for (int o = 1; o < 256; o <<= 1) {
    int a = (tid >= o) ? sc[tid - o] : 0;
    __syncthreads();
    sc[tid] += a;
    __syncthreads();
  }
  int excl = sc[tid] - c;
  offb[tid] = excl;
  lcur[tid] = excl;
  __syncthreads();
  for (int base = 0; base < NTOK; base += 256) {
    int tok = base + tid;
    int e1 = gidx[tok * 2], e2 = gidx[tok * 2 + 1];
    int s1 = atomicAdd(&lcur[e1], 1);
    tokslot[tok * 2] = s1; slottok[s1] = tok;
    int s2 = atomicAdd(&lcur[e2], 1);
    tokslot[tok * 2 + 1] = s2; slottok[s2] = tok;
  }
}

// ================= k_exp: one block per expert ==============================
__global__ __launch_bounds__(512) void k_exp(const float* __restrict__ h2buf,
                                             const int* __restrict__ slottok,
                                             const int* __restrict__ cnt,
                                             const int* __restrict__ offb,
                                             const float* __restrict__ expW,
                                             float* __restrict__ ybuf) {
  const int e = blockIdx.x;
  const int n = cnt[e];
  if (n == 0) return;
  const int base = offb[e];
  const int tid = threadIdx.x;
  const int j = tid & 127, g = tid >> 7;   // g: token quarter (4 tokens each)
  __shared__ __align__(16) float hT[128 * 20];  // stride 20: 16B-aligned + fewer conflicts
  const float* Wp = expW + (size_t)e * Dd * Dd + j;
  for (int t0 = 0; t0 < n; t0 += 16) {
    int m = n - t0; if (m > 16) m = 16;
    __syncthreads();
    for (int tt = g; tt < m; tt += 4) {
      int tok = slottok[base + t0 + tt];
      hT[j * 20 + tt] = h2buf[tok * Dd + j];
    }
    __syncthreads();
    float acc[4] = {0, 0, 0, 0};
#pragma unroll 8
    for (int i = 0; i < 128; i++) {
      float w = Wp[i * Dd];
      float4 h4 = *(const float4*)&hT[i * 20 + g * 4];
      acc[0] += h4.x * w; acc[1] += h4.y * w; acc[2] += h4.z * w; acc[3] += h4.w * w;
    }
#pragma unroll
    for (int k = 0; k < 4; k++) {
      int tt = g * 4 + k;
      if (tt < m) ybuf[(size_t)(base + t0 + tt) * Dd + j] = acc[k];
    }
  }
}

// ================= k_post ===================================================
__global__ __launch_bounds__(512) void k_post(
    const float* __restrict__ xnbuf, const float* __restrict__ ybuf,
    const int* __restrict__ tokslot, const float* __restrict__ gw,
    const float* __restrict__ m1W, const float* __restrict__ m1b,
    const float* __restrict__ m2W, const float* __restrict__ m2b,
    float* __restrict__ out) {
  const int tid = threadIdx.x;
  const int j = tid & 127, g = tid >> 7;
  const int lane = tid & 63;
  const int n0 = blockIdx.x * TPB;

  __shared__ float4 y1T[128], y2T[128], inT[128], sT[128];
  __shared__ float4 part[3][128];
  __shared__ float4 rtmp[2];
  __shared__ int sSlot[4][2];
  __shared__ float sWt[4][2];

  if (tid < 4) {
    sSlot[tid][0] = tokslot[(n0 + tid) * 2];
    sSlot[tid][1] = tokslot[(n0 + tid) * 2 + 1];
    sWt[tid][0] = gw[(n0 + tid) * 2];
    sWt[tid][1] = gw[(n0 + tid) * 2 + 1];
  }
  __syncthreads();

  {  // thread (j,g) handles token g
    float y1 = ybuf[(size_t)sSlot[g][0] * Dd + j];
    float y2 = ybuf[(size_t)sSlot[g][1] * Dd + j];
    ((float*)&y1T[j])[g] = y1;
    ((float*)&y2T[j])[g] = y2;
    ((float*)&inT[j])[g] = sWt[g][0] * y1 + sWt[g][1] * y2;
  }
  __syncthreads();

  // m1/m2 dual GEMV (g0,g1: m1W halves; g2,g3: m2W halves) on inT
  {
    float a0 = 0, a1 = 0, a2 = 0, a3 = 0;
    const float* Wp = (g < 2 ? m1W : m2W) + ((g & 1) * 64) * Dd + j;
#pragma unroll 16
    for (int i = 0; i < 64; i++) {
      float4 h4 = inT[(g & 1) * 64 + i];
      float w = Wp[i * Dd];
      a0 += h4.x * w; a1 += h4.y * w; a2 += h4.z * w; a3 += h4.w * w;
    }
    if (g) part[g - 1][j] = make_float4(a0, a1, a2, a3);
    __syncthreads();
    if (g == 0) {
      float b1 = m1b[j], b2 = m2b[j];
      float4 p0 = part[0][j], p1 = part[1][j], p2 = part[2][j];
      float gv[4], uv[4];
      gv[0] = a0 + p0.x + b1; gv[1] = a1 + p0.y + b1;
      gv[2] = a2 + p0.z + b1; gv[3] = a3 + p0.w + b1;
      uv[0] = p1.x + p2.x + b2; uv[1] = p1.y + p2.y + b2;
      uv[2] = p1.z + p2.z + b2; uv[3] = p1.w + p2.w + b2;
#pragma unroll
      for (int t = 0; t < 4; t++) {
        float sv = gv[t] * sigm(gv[t]) * uv[t];
        ((float*)&sT[j])[t] = sv;
        out[(n0 + t) * Dd + j] = xnbuf[(n0 + t) * Dd + j] + sv;
      }
    }
    __syncthreads();
  }

  // wvar + consensus
  if (tid < 128) {
    float v[4];
#pragma unroll
    for (int t = 0; t < 4; t++) {
      float sv = ((const float*)&sT[j])[t];
      float d1 = ((const float*)&y1T[j])[t] - sv;
      float d2 = ((const float*)&y2T[j])[t] - sv;
      v[t] = sWt[t][0] * d1 * d1 + sWt[t][1] * d2 * d2;
    }
#pragma unroll
    for (int o = 32; o > 0; o >>= 1) {
#pragma unroll
      for (int t = 0; t < 4; t++) v[t] += __shfl_xor(v[t], o, 64);
    }
    if (lane == 0) rtmp[tid >> 6] = make_float4(v[0], v[1], v[2], v[3]);
  }
  __syncthreads();
  if (tid < 4) {
    float s = ((const float*)&rtmp[0])[tid] + ((const float*)&rtmp[1])[tid];
    out[NTOK * Dd + n0 + tid] = expf(-s * (1.f / 128.f));
  }
}

extern "C" void kernel_launch(void* const* d_in, const int* in_sizes, int n_in,
                              void* d_out, int out_size, void* d_ws, size_t ws_size,
                              hipStream_t stream) {
  const float* x   = (const float*)d_in[0];
  const float* g1  = (const float*)d_in[1];
  const float* qW  = (const float*)d_in[2];
  const float* qb  = (const float*)d_in[3];
  const float* kdW = (const float*)d_in[4];
  const float* kdb = (const float*)d_in[5];
  const float* kuW = (const float*)d_in[6];
  const float* kub = (const float*)d_in[7];
  const float* oW  = (const float*)d_in[8];
  const float* ob  = (const float*)d_in[9];
  const float* rot = (const float*)d_in[10];
  const float* tqs = (const float*)d_in[11];
  const float* s1W = (const float*)d_in[12];
  const float* s1b = (const float*)d_in[13];
  const float* s2W = (const float*)d_in[14];
  const float* s2b = (const float*)d_in[15];
  const float* g2  = (const float*)d_in[16];
  const float* gW  = (const float*)d_in[17];
  const float* gb  = (const float*)d_in[18];
  const float* eW  = (const float*)d_in[19];
  const float* m1W = (const float*)d_in[20];
  const float* m1b = (const float*)d_in[21];
  const float* m2W = (const float*)d_in[22];
  const float* m2b = (const float*)d_in[23];
  float* out = (float*)d_out;
  float* ws  = (float*)d_ws;

  float* qbuf  = ws;                       // 262144
  float* kvbuf = ws + 262144;              // 524288
  float* ybuf  = ws;                       // aliases qbuf+kvbuf (dead by then)
  float* ctx   = ws + 786432;              // 8192
  float* ksum  = ctx + 8192;               // 512
  float* h2buf = ksum + 512;               // 262144
  float* xnbuf = h2buf + 262144;           // 262144
  float* gw    = xnbuf + 262144;           // 4096
  int*   gidx    = (int*)(gw + 4096);      // 4096
  int*   cnt     = gidx + 4096;            // 256
  int*   offb    = cnt + 256;              // 256
  int*   slottok = offb + 256;             // 4096
  int*   tokslot = slottok + 4096;         // 4096

  k_pre<<<NTOK / TPB, 512, 0, stream>>>(x, g1, qW, qb, kdW, kdb, kuW, kub,
                                        qbuf, kvbuf, ctx, ksum, cnt);
  k_ctx<<<256, 256, 0, stream>>>(kvbuf, ctx, ksum);
  k_mid<<<NTOK / TPB, 512, 0, stream>>>(x, qbuf, ctx, ksum, oW, ob, rot, tqs,
                                        s1W, s1b, s2W, s2b, g2, gW, gb,
                                        xnbuf, h2buf, gw, gidx, cnt);
  k_route<<<1, 256, 0, stream>>>(cnt, gidx, offb, slottok, tokslot);
  k_exp<<<NE, 512, 0, stream>>>(h2buf, slottok, cnt, offb, eW, ybuf);
  k_post<<<NTOK / TPB, 512, 0, stream>>>(xnbuf, ybuf, tokslot, gw,
                                         m1W, m1b, m2W, m2b, out);
}

// Round 4
// 168.496 us; speedup vs baseline: 1.2145x; 1.0214x over previous
//
#include <hip/hip_runtime.h>
#include <hip/hip_bf16.h>
#include <math.h>

static constexpr int Dd   = 128;
static constexpr int NH   = 8;
static constexpr int HD   = 16;
static constexpr int NE   = 256;
static constexpr int RR   = 32;
static constexpr int BB   = 4;
static constexpr int TT   = 512;
static constexpr int NTOK = BB * TT;   // 2048
static constexpr int TPB  = 4;
static constexpr int SLOTS = 256;      // per-expert slot cap (mean load ~16)
#define EPSF 1e-6f

__device__ __forceinline__ float elu1(float v) { return v > 0.f ? v + 1.f : expf(v); }
__device__ __forceinline__ float sigm(float v) { return 1.f / (1.f + expf(-v)); }

// ===== k_init: precompute oR=oW@rot, bR=ob@rot, kvW=kdW@kuW, bkv=kdb@kuW+kub
//       and zero ctx/ksum/cnt. grid=193 x 256 threads.
__global__ __launch_bounds__(256) void k_init(
    const float* __restrict__ oW, const float* __restrict__ ob,
    const float* __restrict__ rot,
    const float* __restrict__ kdW, const float* __restrict__ kdb,
    const float* __restrict__ kuW, const float* __restrict__ kub,
    float* __restrict__ oR, float* __restrict__ bR,
    float* __restrict__ kvW, float* __restrict__ bkv,
    float* __restrict__ ctx, float* __restrict__ ksum, int* __restrict__ cnt) {
  const int blk = blockIdx.x, tid = threadIdx.x;
  if (blk < 64) {                       // oR: 128x128, K=128
    int row = blk * 2 + (tid >> 7), col = tid & 127;
    const float* ow = oW + row * 128;
    float acc = 0.f;
#pragma unroll 8
    for (int k = 0; k < 128; k++) acc += ow[k] * rot[k * 128 + col];
    oR[row * 128 + col] = acc;
  } else if (blk == 64) {               // bR, bkv, zeroing
    if (tid < 128) {
      float acc = 0.f;
#pragma unroll 8
      for (int k = 0; k < 128; k++) acc += ob[k] * rot[k * 128 + tid];
      bR[tid] = acc;
    }
    {
      float acc = kub[tid];
#pragma unroll
      for (int k = 0; k < 32; k++) acc += kdb[k] * kuW[k * 256 + tid];
      bkv[tid] = acc;
    }
    for (int i = tid; i < 32 * 256; i += 256) ctx[i] = 0.f;
    for (int i = tid; i < 512; i += 256) ksum[i] = 0.f;
    cnt[tid] = 0;
  } else {                              // kvW: 128x256, K=32
    int idx = (blk - 65) * 256 + tid;
    int row = idx >> 8, col = idx & 255;
    const float* kw = kdW + row * 32;
    float acc = 0.f;
#pragma unroll
    for (int k = 0; k < 32; k++) acc += kw[k] * kuW[k * 256 + col];
    kvW[row * 256 + col] = acc;
  }
}

// ===== k_pre: [sumsq(x) || (g1*x) @ [qW | kvW] ] -> r-scale -> elu -> q,kv
// 768 threads: tid<256: q cols (K-split-2); tid>=256: kv cols (K-split-2)
__global__ __launch_bounds__(768) void k_pre(
    const float* __restrict__ x, const float* __restrict__ g1,
    const float* __restrict__ qW, const float* __restrict__ qb,
    const float* __restrict__ kvW, const float* __restrict__ bkv,
    float* __restrict__ qbuf, float* __restrict__ kvbuf) {
  const int tid = threadIdx.x;
  const int lane = tid & 63;
  const int n0 = blockIdx.x * TPB;

  __shared__ float4 xgT[128];
  __shared__ float4 qpart[128];
  __shared__ float4 kvpart[256];
  __shared__ float4 rtmp[2];

  // prep: xgT = (g1*x) transposed; sumsq partials
  if (tid < 128) {
    int j = tid;
    float g1j = g1[j];
    float v[4], xg[4];
#pragma unroll
    for (int t = 0; t < 4; t++) {
      float xv = x[(n0 + t) * Dd + j];
      v[t] = xv * xv;
      xg[t] = xv * g1j;
    }
    xgT[j] = make_float4(xg[0], xg[1], xg[2], xg[3]);
#pragma unroll
    for (int o = 32; o > 0; o >>= 1) {
#pragma unroll
      for (int t = 0; t < 4; t++) v[t] += __shfl_xor(v[t], o, 64);
    }
    if (lane == 0) rtmp[tid >> 6] = make_float4(v[0], v[1], v[2], v[3]);
  }
  __syncthreads();

  float a0 = 0, a1 = 0, a2 = 0, a3 = 0;
  const bool isq = tid < 256;
  int j, kh;
  if (isq) {
    j = tid & 127; kh = tid >> 7;
    const float* Wp = qW + (kh * 64) * Dd + j;
    const float4* hb = xgT + kh * 64;
#pragma unroll 16
    for (int i = 0; i < 64; i++) {
      float4 h4 = hb[i];
      float w = Wp[i * Dd];
      a0 += h4.x * w; a1 += h4.y * w; a2 += h4.z * w; a3 += h4.w * w;
    }
    if (kh) qpart[j] = make_float4(a0, a1, a2, a3);
  } else {
    int u = tid - 256;
    j = u & 255; kh = u >> 8;
    const float* Wp = kvW + (kh * 64) * 256 + j;
    const float4* hb = xgT + kh * 64;
#pragma unroll 16
    for (int i = 0; i < 64; i++) {
      float4 h4 = hb[i];
      float w = Wp[i * 256];
      a0 += h4.x * w; a1 += h4.y * w; a2 += h4.z * w; a3 += h4.w * w;
    }
    if (kh) kvpart[j] = make_float4(a0, a1, a2, a3);
  }
  __syncthreads();

  if (kh == 0) {
    float r[4];
#pragma unroll
    for (int t = 0; t < 4; t++) {
      float ss = ((const float*)&rtmp[0])[t] + ((const float*)&rtmp[1])[t];
      r[t] = rsqrtf(ss * (1.f / 128.f) + EPSF);
    }
    if (isq) {
      float4 p = qpart[j];
      float bb = qb[j];
      qbuf[(n0 + 0) * Dd + j] = elu1((a0 + p.x) * r[0] + bb);
      qbuf[(n0 + 1) * Dd + j] = elu1((a1 + p.y) * r[1] + bb);
      qbuf[(n0 + 2) * Dd + j] = elu1((a2 + p.z) * r[2] + bb);
      qbuf[(n0 + 3) * Dd + j] = elu1((a3 + p.w) * r[3] + bb);
    } else {
      float4 p = kvpart[j];
      float bb = bkv[j];
      bool isk = (j & 31) < 16;
      float v0 = (a0 + p.x) * r[0] + bb, v1 = (a1 + p.y) * r[1] + bb;
      float v2 = (a2 + p.z) * r[2] + bb, v3 = (a3 + p.w) * r[3] + bb;
      kvbuf[(n0 + 0) * 256 + j] = isk ? elu1(v0) : v0;
      kvbuf[(n0 + 1) * 256 + j] = isk ? elu1(v1) : v1;
      kvbuf[(n0 + 2) * 256 + j] = isk ? elu1(v2) : v2;
      kvbuf[(n0 + 3) * 256 + j] = isk ? elu1(v3) : v3;
    }
  }
}

// ===== k_ctx: 256 blocks = 32 (b,h) x 8 T-chunks, atomic accumulate ========
__global__ __launch_bounds__(256) void k_ctx(const float* __restrict__ kv,
                                             float* __restrict__ ctx,
                                             float* __restrict__ ksum) {
  const int blk = blockIdx.x;
  const int bh = blk >> 3, c = blk & 7;
  const int b = bh >> 3, h = bh & 7;
  const int tid = threadIdx.x;
  const int d = tid >> 4, e = tid & 15;
  __shared__ float sh[64 * 32];
#pragma unroll
  for (int r = 0; r < 8; r++) {
    int lin = r * 256 + tid;
    int tok = lin >> 5, off = lin & 31;
    sh[lin] = kv[((b * TT + c * 64 + tok) * 256) + h * 32 + off];
  }
  __syncthreads();
  float acc = 0.f, ks = 0.f;
#pragma unroll 4
  for (int t = 0; t < 64; t++) {
    float kk = sh[t * 32 + d];
    acc += kk * sh[t * 32 + 16 + e];
    ks += kk;
  }
  atomicAdd(&ctx[bh * 256 + d * 16 + e], acc);
  if (e == 0) atomicAdd(&ksum[bh * 16 + d], ks);
}

// ===== k_mid: attn -> oR(+quant) -> s1s2(+res) -> rms2||gate -> top2+scatter
__global__ __launch_bounds__(512) void k_mid(
    const float* __restrict__ x, const float* __restrict__ qbuf,
    const float* __restrict__ ctx, const float* __restrict__ ksum,
    const float* __restrict__ oR, const float* __restrict__ bR,
    const float* __restrict__ tqs,
    const float* __restrict__ s1W, const float* __restrict__ s1b,
    const float* __restrict__ s2W, const float* __restrict__ s2b,
    const float* __restrict__ g2, const float* __restrict__ gateW,
    const float* __restrict__ gateb,
    float* __restrict__ xnbuf, float* __restrict__ h2buf,
    float* __restrict__ gw, int* __restrict__ tokslot,
    int* __restrict__ slottok, int* __restrict__ cnt) {
  const int tid = threadIdx.x;
  const int j = tid & 127, g = tid >> 7;
  const int lane = tid & 63;
  const int n0 = blockIdx.x * TPB;
  const int b = n0 >> 9;

  __shared__ float4 bufA[128], bufB[128];
  __shared__ float4 part[3][128];
  __shared__ float4 gpart[256];
  __shared__ float4 rtmp[2];
  __shared__ float wvS[4][4]; __shared__ int wiS[4][4];
  __shared__ float zS[4][4];

  // preload residual x (hides latency over later phases)
  float xres[4];
  if (tid < 128) {
#pragma unroll
    for (int t = 0; t < 4; t++) xres[t] = x[(n0 + t) * Dd + j];
  }

  // phase 1: load q token-transposed
  ((float*)&bufA[j])[g] = qbuf[(n0 + g) * Dd + j];
  __syncthreads();

  // phase 2: attention apply -> bufB (tid<128, K=16)
  if (tid < 128) {
    int h = j >> 4, e = j & 15;
    const float* cpt = ctx + (b * NH + h) * 256;
    const float* kpt = ksum + (b * NH + h) * 16;
    float num[4] = {0, 0, 0, 0}, den[4] = {0, 0, 0, 0};
#pragma unroll
    for (int d = 0; d < 16; d++) {
      float cx = cpt[d * 16 + e], ks = kpt[d];
      float4 q4 = bufA[h * 16 + d];
      num[0] += q4.x * cx; num[1] += q4.y * cx; num[2] += q4.z * cx; num[3] += q4.w * cx;
      den[0] += q4.x * ks; den[1] += q4.y * ks; den[2] += q4.z * ks; den[3] += q4.w * ks;
    }
#pragma unroll
    for (int t = 0; t < 4; t++) ((float*)&bufB[j])[t] = num[t] / (den[t] + EPSF);
  }
  __syncthreads();

  // phase 3: z = bufB @ oR + bR; quant: clamp(z,±mag)*tqs -> bufA
  {
    float a0 = 0, a1 = 0, a2 = 0, a3 = 0;
    const float* Wp = oR + (g * 32) * Dd + j;
#pragma unroll 16
    for (int i = 0; i < 32; i++) {
      float4 h4 = bufB[g * 32 + i];
      float w = Wp[i * Dd];
      a0 += h4.x * w; a1 += h4.y * w; a2 += h4.z * w; a3 += h4.w * w;
    }
    if (g) part[g - 1][j] = make_float4(a0, a1, a2, a3);
    __syncthreads();
    float tot[4];
    if (g == 0) {
      float4 p0 = part[0][j], p1 = part[1][j], p2 = part[2][j];
      float bb = bR[j];
      tot[0] = a0 + p0.x + p1.x + p2.x + bb; tot[1] = a1 + p0.y + p1.y + p2.y + bb;
      tot[2] = a2 + p0.z + p1.z + p2.z + bb; tot[3] = a3 + p0.w + p1.w + p2.w + bb;
      float v[4];
#pragma unroll
      for (int t = 0; t < 4; t++) v[t] = tot[t] * tot[t];
#pragma unroll
      for (int o = 32; o > 0; o >>= 1) {
#pragma unroll
        for (int t = 0; t < 4; t++) v[t] += __shfl_xor(v[t], o, 64);
      }
      if (lane == 0) rtmp[tid >> 6] = make_float4(v[0], v[1], v[2], v[3]);
    }
    __syncthreads();
    if (g == 0) {
      float scj = tqs[j];
#pragma unroll
      for (int t = 0; t < 4; t++) {
        float ss = ((const float*)&rtmp[0])[t] + ((const float*)&rtmp[1])[t];
        float mag = sqrtf(ss * (1.f / 128.f) + EPSF);
        float zc = fminf(fmaxf(tot[t], -mag), mag);
        ((float*)&bufA[j])[t] = zc * scj;
      }
    }
    __syncthreads();
  }

  // phase 4: s1/s2 dual GEMV on bufA -> xn (+ residual); bufB = g2*xn; rtmp=sumsq
  {
    float a0 = 0, a1 = 0, a2 = 0, a3 = 0;
    const float* Wp = (g < 2 ? s1W : s2W) + ((g & 1) * 64) * Dd + j;
#pragma unroll 16
    for (int i = 0; i < 64; i++) {
      float4 h4 = bufA[(g & 1) * 64 + i];
      float w = Wp[i * Dd];
      a0 += h4.x * w; a1 += h4.y * w; a2 += h4.z * w; a3 += h4.w * w;
    }
    if (g) part[g - 1][j] = make_float4(a0, a1, a2, a3);
    __syncthreads();
    if (g == 0) {
      float b1 = s1b[j], b2 = s2b[j];
      float4 p0 = part[0][j], p1 = part[1][j], p2 = part[2][j];
      float gv[4], uv[4], xn[4], v[4];
      gv[0] = a0 + p0.x + b1; gv[1] = a1 + p0.y + b1;
      gv[2] = a2 + p0.z + b1; gv[3] = a3 + p0.w + b1;
      uv[0] = p1.x + p2.x + b2; uv[1] = p1.y + p2.y + b2;
      uv[2] = p1.z + p2.z + b2; uv[3] = p1.w + p2.w + b2;
      float g2j = g2[j];
#pragma unroll
      for (int t = 0; t < 4; t++) {
        xn[t] = xres[t] + gv[t] * sigm(gv[t]) * uv[t];
        xnbuf[(n0 + t) * Dd + j] = xn[t];
        ((float*)&bufB[j])[t] = g2j * xn[t];   // pre-r2 h2
        v[t] = xn[t] * xn[t];
      }
#pragma unroll
      for (int o = 32; o > 0; o >>= 1) {
#pragma unroll
        for (int t = 0; t < 4; t++) v[t] += __shfl_xor(v[t], o, 64);
      }
      if (lane == 0) rtmp[tid >> 6] = make_float4(v[0], v[1], v[2], v[3]);
    }
    __syncthreads();
  }

  // phase 5: gate logits on bufB (K-split-2, 256 cols); r2 applied at epilogue
  float val[4];
  float r2[4];
  {
    int col = tid & 255, kh = tid >> 8;
    float a0 = 0, a1 = 0, a2 = 0, a3 = 0;
    const float* Wp = gateW + (kh * 64) * NE + col;
#pragma unroll 16
    for (int i = 0; i < 64; i++) {
      float4 h4 = bufB[kh * 64 + i];
      float w = Wp[i * NE];
      a0 += h4.x * w; a1 += h4.y * w; a2 += h4.z * w; a3 += h4.w * w;
    }
    if (kh) gpart[col] = make_float4(a0, a1, a2, a3);
    __syncthreads();
#pragma unroll
    for (int t = 0; t < 4; t++) {
      float ss = ((const float*)&rtmp[0])[t] + ((const float*)&rtmp[1])[t];
      r2[t] = rsqrtf(ss * (1.f / 128.f) + EPSF);
    }
    if (!kh) {
      float4 p = gpart[col];
      float bb = gateb[col];
      val[0] = (a0 + p.x) * r2[0] + bb; val[1] = (a1 + p.y) * r2[1] + bb;
      val[2] = (a2 + p.z) * r2[2] + bb; val[3] = (a3 + p.w) * r2[3] + bb;
    }
    if (tid < 128) {  // h2 = r2 * g2 * xn
#pragma unroll
      for (int t = 0; t < 4; t++)
        h2buf[(n0 + t) * Dd + j] = ((const float*)&bufB[j])[t] * r2[t];
    }
  }
  __syncthreads();

  // top-2 over 256 logits (tid<256)
  float m1[4]; int i1[4];
  {
    if (tid < 256) {
      float bv[4]; int bi[4];
#pragma unroll
      for (int t = 0; t < 4; t++) { bv[t] = val[t]; bi[t] = tid; }
#pragma unroll
      for (int o = 32; o > 0; o >>= 1) {
#pragma unroll
        for (int t = 0; t < 4; t++) {
          float wv = __shfl_xor(bv[t], o, 64);
          int wi = __shfl_xor(bi[t], o, 64);
          if (wv > bv[t] || (wv == bv[t] && wi < bi[t])) { bv[t] = wv; bi[t] = wi; }
        }
      }
      if (lane == 0) {
#pragma unroll
        for (int t = 0; t < 4; t++) { wvS[tid >> 6][t] = bv[t]; wiS[tid >> 6][t] = bi[t]; }
      }
    }
    __syncthreads();
    if (tid < 256) {
#pragma unroll
      for (int t = 0; t < 4; t++) {
        m1[t] = wvS[0][t]; i1[t] = wiS[0][t];
#pragma unroll
        for (int w = 1; w < 4; w++) {
          float cv = wvS[w][t]; int ci = wiS[w][t];
          if (cv > m1[t] || (cv == m1[t] && ci < i1[t])) { m1[t] = cv; i1[t] = ci; }
        }
      }
    }
    __syncthreads();
  }
  float m2[4]; int i2[4];
  {
    if (tid < 256) {
      float bv[4]; int bi[4];
#pragma unroll
      for (int t = 0; t < 4; t++) {
        bv[t] = (tid == i1[t]) ? -INFINITY : val[t];
        bi[t] = tid;
      }
#pragma unroll
      for (int o = 32; o > 0; o >>= 1) {
#pragma unroll
        for (int t = 0; t < 4; t++) {
          float wv = __shfl_xor(bv[t], o, 64);
          int wi = __shfl_xor(bi[t], o, 64);
          if (wv > bv[t] || (wv == bv[t] && wi < bi[t])) { bv[t] = wv; bi[t] = wi; }
        }
      }
      if (lane == 0) {
#pragma unroll
        for (int t = 0; t < 4; t++) { wvS[tid >> 6][t] = bv[t]; wiS[tid >> 6][t] = bi[t]; }
      }
    }
    __syncthreads();
    if (tid < 256) {
#pragma unroll
      for (int t = 0; t < 4; t++) {
        m2[t] = wvS[0][t]; i2[t] = wiS[0][t];
#pragma unroll
        for (int w = 1; w < 4; w++) {
          float cv = wvS[w][t]; int ci = wiS[w][t];
          if (cv > m2[t] || (cv == m2[t] && ci < i2[t])) { m2[t] = cv; i2[t] = ci; }
        }
      }
    }
    __syncthreads();
  }
  {
    if (tid < 256) {
      float v[4];
#pragma unroll
      for (int t = 0; t < 4; t++) v[t] = expf(val[t] - m1[t]);
#pragma unroll
      for (int o = 32; o > 0; o >>= 1) {
#pragma unroll
        for (int t = 0; t < 4; t++) v[t] += __shfl_xor(v[t], o, 64);
      }
      if (lane == 0) {
#pragma unroll
        for (int t = 0; t < 4; t++) zS[tid >> 6][t] = v[t];
      }
    }
    __syncthreads();
  }
  if (tid < 4) {
    int t = tid, tok = n0 + t;
    float Z = zS[0][t] + zS[1][t] + zS[2][t] + zS[3][t];
    float p1 = 1.f / Z;
    float p2 = expf(m2[t] - m1[t]) / Z;
    float s = p1 + p2 + EPSF;
    int e1 = i1[t], e2 = i2[t];
    int s1 = atomicAdd(&cnt[e1], 1); if (s1 > SLOTS - 1) s1 = SLOTS - 1;
    int s2 = atomicAdd(&cnt[e2], 1); if (s2 > SLOTS - 1) s2 = SLOTS - 1;
    int sl1 = e1 * SLOTS + s1, sl2 = e2 * SLOTS + s2;
    slottok[sl1] = tok; slottok[sl2] = tok;
    tokslot[tok * 2] = sl1; tokslot[tok * 2 + 1] = sl2;
    gw[tok * 2] = p1 / s; gw[tok * 2 + 1] = p2 / s;
  }
}

// ===== k_exp: one block per expert, fixed slot base ==========================
__global__ __launch_bounds__(512) void k_exp(const float* __restrict__ h2buf,
                                             const int* __restrict__ slottok,
                                             const int* __restrict__ cnt,
                                             const float* __restrict__ expW,
                                             float* __restrict__ ybuf) {
  const int e = blockIdx.x;
  int n = cnt[e]; if (n > SLOTS) n = SLOTS;
  if (n == 0) return;
  const int base = e * SLOTS;
  const int tid = threadIdx.x;
  const int j = tid & 127, g = tid >> 7;
  __shared__ __align__(16) float hT[128 * 20];
  const float* Wp = expW + (size_t)e * Dd * Dd + j;
  for (int t0 = 0; t0 < n; t0 += 16) {
    int m = n - t0; if (m > 16) m = 16;
    __syncthreads();
    for (int tt = g; tt < m; tt += 4) {
      int tok = slottok[base + t0 + tt];
      hT[j * 20 + tt] = h2buf[tok * Dd + j];
    }
    __syncthreads();
    float acc[4] = {0, 0, 0, 0};
#pragma unroll 8
    for (int i = 0; i < 128; i++) {
      float w = Wp[i * Dd];
      float4 h4 = *(const float4*)&hT[i * 20 + g * 4];
      acc[0] += h4.x * w; acc[1] += h4.y * w; acc[2] += h4.z * w; acc[3] += h4.w * w;
    }
#pragma unroll
    for (int k = 0; k < 4; k++) {
      int tt = g * 4 + k;
      if (tt < m) ybuf[(size_t)(base + t0 + tt) * Dd + j] = acc[k];
    }
  }
}

// ===== k_post ================================================================
__global__ __launch_bounds__(512) void k_post(
    const float* __restrict__ xnbuf, const float* __restrict__ ybuf,
    const int* __restrict__ tokslot, const float* __restrict__ gw,
    const float* __restrict__ m1W, const float* __restrict__ m1b,
    const float* __restrict__ m2W, const float* __restrict__ m2b,
    float* __restrict__ out) {
  const int tid = threadIdx.x;
  const int j = tid & 127, g = tid >> 7;
  const int lane = tid & 63;
  const int n0 = blockIdx.x * TPB;

  __shared__ float4 y1T[128], y2T[128], inT[128], sT[128];
  __shared__ float4 part[3][128];
  __shared__ float4 rtmp[2];
  __shared__ int sSlot[4][2];
  __shared__ float sWt[4][2];

  if (tid < 4) {
    sSlot[tid][0] = tokslot[(n0 + tid) * 2];
    sSlot[tid][1] = tokslot[(n0 + tid) * 2 + 1];
    sWt[tid][0] = gw[(n0 + tid) * 2];
    sWt[tid][1] = gw[(n0 + tid) * 2 + 1];
  }
  __syncthreads();

  {
    float y1 = ybuf[(size_t)sSlot[g][0] * Dd + j];
    float y2 = ybuf[(size_t)sSlot[g][1] * Dd + j];
    ((float*)&y1T[j])[g] = y1;
    ((float*)&y2T[j])[g] = y2;
    ((float*)&inT[j])[g] = sWt[g][0] * y1 + sWt[g][1] * y2;
  }
  __syncthreads();

  {
    float a0 = 0, a1 = 0, a2 = 0, a3 = 0;
    const float* Wp = (g < 2 ? m1W : m2W) + ((g & 1) * 64) * Dd + j;
#pragma unroll 16
    for (int i = 0; i < 64; i++) {
      float4 h4 = inT[(g & 1) * 64 + i];
      float w = Wp[i * Dd];
      a0 += h4.x * w; a1 += h4.y * w; a2 += h4.z * w; a3 += h4.w * w;
    }
    if (g) part[g - 1][j] = make_float4(a0, a1, a2, a3);
    __syncthreads();
    if (g == 0) {
      float b1 = m1b[j], b2 = m2b[j];
      float4 p0 = part[0][j], p1 = part[1][j], p2 = part[2][j];
      float gv[4], uv[4];
      gv[0] = a0 + p0.x + b1; gv[1] = a1 + p0.y + b1;
      gv[2] = a2 + p0.z + b1; gv[3] = a3 + p0.w + b1;
      uv[0] = p1.x + p2.x + b2; uv[1] = p1.y + p2.y + b2;
      uv[2] = p1.z + p2.z + b2; uv[3] = p1.w + p2.w + b2;
#pragma unroll
      for (int t = 0; t < 4; t++) {
        float sv = gv[t] * sigm(gv[t]) * uv[t];
        ((float*)&sT[j])[t] = sv;
        out[(n0 + t) * Dd + j] = xnbuf[(n0 + t) * Dd + j] + sv;
      }
    }
    __syncthreads();
  }

  if (tid < 128) {
    float v[4];
#pragma unroll
    for (int t = 0; t < 4; t++) {
      float sv = ((const float*)&sT[j])[t];
      float d1 = ((const float*)&y1T[j])[t] - sv;
      float d2 = ((const float*)&y2T[j])[t] - sv;
      v[t] = sWt[t][0] * d1 * d1 + sWt[t][1] * d2 * d2;
    }
#pragma unroll
    for (int o = 32; o > 0; o >>= 1) {
#pragma unroll
      for (int t = 0; t < 4; t++) v[t] += __shfl_xor(v[t], o, 64);
    }
    if (lane == 0) rtmp[tid >> 6] = make_float4(v[0], v[1], v[2], v[3]);
  }
  __syncthreads();
  if (tid < 4) {
    float s = ((const float*)&rtmp[0])[tid] + ((const float*)&rtmp[1])[tid];
    out[NTOK * Dd + n0 + tid] = expf(-s * (1.f / 128.f));
  }
}

extern "C" void kernel_launch(void* const* d_in, const int* in_sizes, int n_in,
                              void* d_out, int out_size, void* d_ws, size_t ws_size,
                              hipStream_t stream) {
  const float* x   = (const float*)d_in[0];
  const float* g1  = (const float*)d_in[1];
  const float* qW  = (const float*)d_in[2];
  const float* qb  = (const float*)d_in[3];
  const float* kdW = (const float*)d_in[4];
  const float* kdb = (const float*)d_in[5];
  const float* kuW = (const float*)d_in[6];
  const float* kub = (const float*)d_in[7];
  const float* oW  = (const float*)d_in[8];
  const float* ob  = (const float*)d_in[9];
  const float* rot = (const float*)d_in[10];
  const float* tqs = (const float*)d_in[11];
  const float* s1W = (const float*)d_in[12];
  const float* s1b = (const float*)d_in[13];
  const float* s2W = (const float*)d_in[14];
  const float* s2b = (const float*)d_in[15];
  const float* g2  = (const float*)d_in[16];
  const float* gW  = (const float*)d_in[17];
  const float* gb  = (const float*)d_in[18];
  const float* eW  = (const float*)d_in[19];
  const float* m1W = (const float*)d_in[20];
  const float* m1b = (const float*)d_in[21];
  const float* m2W = (const float*)d_in[22];
  const float* m2b = (const float*)d_in[23];
  float* out = (float*)d_out;
  float* ws  = (float*)d_ws;

  // workspace layout (floats)
  float* qbuf   = ws;                     // 262144
  float* kvbuf  = ws + 262144;            // 524288 -> 786432
  float* ctx    = ws + 786432;            // 8192   -> 794624
  float* ksum   = ws + 794624;            // 512    -> 795136
  float* h2buf  = ws + 795136;            // 262144 -> 1057280
  float* xnbuf  = ws + 1057280;           // 262144 -> 1319424
  float* gw     = ws + 1319424;           // 4096   -> 1323520
  float* oRb    = ws + 1323520;           // 16384  -> 1339904
  float* bRb    = ws + 1339904;           // 128    -> 1340032
  float* kvW    = ws + 1340032;           // 32768  -> 1372800
  float* bkv    = ws + 1372800;           // 256    -> 1373056
  int*   cnt     = (int*)(ws + 1373056);  // 256    -> 1373312
  int*   tokslot = (int*)(ws + 1373312);  // 4096   -> 1377408
  int*   slottok = (int*)(ws + 1377408);  // 65536  -> 1442944
  float* ybuf   = ws + 1442944;           // 256*256*128 = 8388608

  k_init<<<193, 256, 0, stream>>>(oW, ob, rot, kdW, kdb, kuW, kub,
                                  oRb, bRb, kvW, bkv, ctx, ksum, cnt);
  k_pre<<<NTOK / TPB, 768, 0, stream>>>(x, g1, qW, qb, kvW, bkv, qbuf, kvbuf);
  k_ctx<<<256, 256, 0, stream>>>(kvbuf, ctx, ksum);
  k_mid<<<NTOK / TPB, 512, 0, stream>>>(x, qbuf, ctx, ksum, oRb, bRb, tqs,
                                        s1W, s1b, s2W, s2b, g2, gW, gb,
                                        xnbuf, h2buf, gw, tokslot, slottok, cnt);
  k_exp<<<NE, 512, 0, stream>>>(h2buf, slottok, cnt, eW, ybuf);
  k_post<<<NTOK / TPB, 512, 0, stream>>>(xnbuf, ybuf, tokslot, gw,
                                         m1W, m1b, m2W, m2b, out);
}